// Round 3
// baseline (662.785 us; speedup 1.0000x reference)
//
#include <hip/hip_runtime.h>
#include <hip/hip_bf16.h>
#include <math.h>

using bf16 = __hip_bfloat16;
typedef __attribute__((ext_vector_type(8))) short short8;
typedef __attribute__((ext_vector_type(4))) float f32x4;

static constexpr int B_ = 4, C_ = 512, L_ = 4096, M_ = 16384;
static constexpr size_t MB = 1ull << 20;

__device__ __forceinline__ float b2f(bf16 v){ return __bfloat162float(v); }
__device__ __forceinline__ bf16  f2b(float v){ return __float2bfloat16(v); }

// async global -> LDS, 16B per lane, lane l lands at ldsbase + l*16
__device__ __forceinline__ void gl_lds16(const bf16* g, bf16* l) {
  __builtin_amdgcn_global_load_lds(
      (const __attribute__((address_space(1))) unsigned int*)g,
      (__attribute__((address_space(3))) unsigned int*)l, 16, 0, 0);
}

// ---------------- weight transpose fp32 -> bf16 (+ zero pad rows of Wt) ----
__global__ __launch_bounds__(256) void transpose_pad(const float* __restrict__ W,
    bf16* __restrict__ Wt, int K, int N, int Npad)
{
  __shared__ float tile[32][33];
  int k0 = blockIdx.x * 32, n0 = blockIdx.y * 32;
  int tx = threadIdx.x, ty = threadIdx.y;
  #pragma unroll
  for (int i = 0; i < 32; i += 8) {
    int k = k0 + ty + i, n = n0 + tx;
    tile[ty + i][tx] = (n < N) ? W[(size_t)k * N + n] : 0.f;
  }
  __syncthreads();
  #pragma unroll
  for (int i = 0; i < 32; i += 8) {
    int n = n0 + ty + i, k = k0 + tx;
    Wt[(size_t)n * K + k] = f2b(tile[tx][ty + i]);
  }
}

// combined bias for [soff(128) | attw(64) | zero(64)]
__global__ void pack_bias_sa(const float* __restrict__ sb,
                             const float* __restrict__ ab, float* __restrict__ bp){
  int i = threadIdx.x;           // 256 threads
  float v = 0.f;
  if (i < 128) v = sb[i]; else if (i < 192) v = ab[i - 128];
  bp[i] = v;
}

// ---------------- GroupNorm stats (sum, sumsq per (b,g)) ----------------
__global__ __launch_bounds__(256) void gn_partial(const float* __restrict__ x,
                                                  float* __restrict__ stats)
{
  int bg = blockIdx.x >> 4;
  int sc = blockIdx.x & 15;
  size_t base = (size_t)bg * 262144 + (size_t)sc * 16384;
  int tid = threadIdx.x;
  float s = 0.f, s2 = 0.f;
  #pragma unroll
  for (int i = 0; i < 8; i++) {
    size_t o = base + ((size_t)i * 256 + tid) * 8;
    float4 a = *reinterpret_cast<const float4*>(&x[o]);
    float4 b = *reinterpret_cast<const float4*>(&x[o + 4]);
    s  += a.x + a.y + a.z + a.w + b.x + b.y + b.z + b.w;
    s2 += a.x*a.x + a.y*a.y + a.z*a.z + a.w*a.w
        + b.x*b.x + b.y*b.y + b.z*b.z + b.w*b.w;
  }
  #pragma unroll
  for (int o = 32; o; o >>= 1) { s += __shfl_xor(s, o, 64); s2 += __shfl_xor(s2, o, 64); }
  __shared__ float ls[4], ls2[4];
  int wave = tid >> 6, lane = tid & 63;
  if (lane == 0) { ls[wave] = s; ls2[wave] = s2; }
  __syncthreads();
  if (tid == 0) {
    atomicAdd(&stats[bg * 2 + 0], ls[0] + ls[1] + ls[2] + ls[3]);
    atomicAdd(&stats[bg * 2 + 1], ls2[0] + ls2[1] + ls2[2] + ls2[3]);
  }
}

// ---------------- GN apply + transpose (B,C,L) -> (B*L, C) bf16 ----------
__global__ __launch_bounds__(256) void gn_apply_t(const float* __restrict__ x,
    const float* __restrict__ stats, const float* __restrict__ gg,
    const float* __restrict__ gb, bf16* __restrict__ xnt)
{
  __shared__ float tile[32][33];
  int b = blockIdx.z, c0 = blockIdx.y * 32, l0 = blockIdx.x * 32;
  int tx = threadIdx.x, ty = threadIdx.y;
  #pragma unroll
  for (int i = 0; i < 32; i += 8) {
    int c = c0 + ty + i, l = l0 + tx;
    int grp = b * 8 + (c >> 6);
    float sum = stats[grp * 2], ss = stats[grp * 2 + 1];
    float mu = sum * (1.f / 262144.f);
    float inv = rsqrtf(ss * (1.f / 262144.f) - mu * mu + 1e-5f);
    float v = x[((size_t)b * 512 + c) * 4096 + l];
    tile[ty + i][tx] = (v - mu) * inv * gg[c] + gb[c];
  }
  __syncthreads();
  #pragma unroll
  for (int i = 0; i < 32; i += 8) {
    int l = l0 + ty + i, c = c0 + tx;
    xnt[((size_t)b * 4096 + l) * 512 + c] = f2b(tile[tx][ty + i]);
  }
}

// ---------------- LayerNorm over C=512: fp32 in, bf16 out, 1 wave/row -----
__global__ __launch_bounds__(256) void layernorm_k(const float* __restrict__ X,
    const float* __restrict__ g, const float* __restrict__ b, bf16* __restrict__ Y)
{
  int row = blockIdx.x * 4 + (threadIdx.x >> 6);
  int lane = threadIdx.x & 63;
  const float* xr = X + (size_t)row * 512 + lane * 8;
  float4 a = *reinterpret_cast<const float4*>(xr);
  float4 c = *reinterpret_cast<const float4*>(xr + 4);
  float v[8] = {a.x, a.y, a.z, a.w, c.x, c.y, c.z, c.w};
  float s = 0.f, s2 = 0.f;
  #pragma unroll
  for (int i = 0; i < 8; i++) { s += v[i]; s2 += v[i] * v[i]; }
  #pragma unroll
  for (int o = 32; o; o >>= 1) { s += __shfl_xor(s, o, 64); s2 += __shfl_xor(s2, o, 64); }
  float mu = s * (1.f / 512.f);
  float inv = rsqrtf(s2 * (1.f / 512.f) - mu * mu + 1e-5f);
  float4 g0 = *reinterpret_cast<const float4*>(&g[lane * 8]);
  float4 g1 = *reinterpret_cast<const float4*>(&g[lane * 8 + 4]);
  float4 b0 = *reinterpret_cast<const float4*>(&b[lane * 8]);
  float4 b1 = *reinterpret_cast<const float4*>(&b[lane * 8 + 4]);
  float gv[8] = {g0.x, g0.y, g0.z, g0.w, g1.x, g1.y, g1.z, g1.w};
  float bv[8] = {b0.x, b0.y, b0.z, b0.w, b1.x, b1.y, b1.z, b1.w};
  bf16 outv[8];
  #pragma unroll
  for (int i = 0; i < 8; i++) outv[i] = f2b((v[i] - mu) * inv * gv[i] + bv[i]);
  *reinterpret_cast<uint4*>(Y + (size_t)row * 512 + lane * 8) =
      *reinterpret_cast<const uint4*>(outv);
}

// ---------------- MFMA GEMM (global_load_lds staging, m97 structure) ------
// C[M,N] = A[M,K] * Bt[N,K]^T + bias (+epi)
// EPI: 0 none | 1 += res[idx] | 3 transpose+residual fp32 out
template<typename TOUT, typename TRES, int EPI>
__global__ __launch_bounds__(256) void gemm_bt(const bf16* __restrict__ A,
    const bf16* __restrict__ Bt, const float* __restrict__ bias,
    const TRES* __restrict__ res, TOUT* __restrict__ Cv, int M, int N, int K)
{
  __shared__ alignas(16) bf16 As[128 * 32];
  __shared__ alignas(16) bf16 Bs[128 * 32];
  const int tid = threadIdx.x;
  const int m0 = blockIdx.y * 128;
  const int n0 = blockIdx.x * 128;
  const int lane = tid & 63;
  const int wave = tid >> 6;
  const int wm = (wave >> 1) * 64;
  const int wn = (wave & 1) * 64;
  const int fr = lane & 15;
  const int fq = lane >> 4;
  const int srow = wave * 32 + (lane >> 2);   // staged row for this lane (issue 0)
  const int scol = (lane & 3) * 8;            // bf16 col offset (16B granule)

  const bf16* ga0 = A  + (size_t)(m0 + srow) * K + scol;
  const bf16* ga1 = ga0 + (size_t)16 * K;
  const bf16* gb0 = Bt + (size_t)(n0 + srow) * K + scol;
  const bf16* gb1 = gb0 + (size_t)16 * K;
  bf16* la0 = &As[wave * 32 * 32];
  bf16* la1 = la0 + 16 * 32;
  bf16* lb0 = &Bs[wave * 32 * 32];
  bf16* lb1 = lb0 + 16 * 32;

  f32x4 acc[4][4];
  #pragma unroll
  for (int i = 0; i < 4; i++)
    #pragma unroll
    for (int j = 0; j < 4; j++) acc[i][j] = (f32x4){0.f, 0.f, 0.f, 0.f};

  for (int kt = 0; kt < K; kt += 32) {
    __syncthreads();
    gl_lds16(ga0, la0); gl_lds16(ga1, la1);
    gl_lds16(gb0, lb0); gl_lds16(gb1, lb1);
    ga0 += 32; ga1 += 32; gb0 += 32; gb1 += 32;
    __syncthreads();
    short8 af[4], bfv[4];
    #pragma unroll
    for (int mi = 0; mi < 4; mi++)
      af[mi] = *reinterpret_cast<const short8*>(&As[(wm + mi * 16 + fr) * 32 + fq * 8]);
    #pragma unroll
    for (int ni = 0; ni < 4; ni++)
      bfv[ni] = *reinterpret_cast<const short8*>(&Bs[(wn + ni * 16 + fr) * 32 + fq * 8]);
    #pragma unroll
    for (int mi = 0; mi < 4; mi++)
      #pragma unroll
      for (int ni = 0; ni < 4; ni++)
        acc[mi][ni] = __builtin_amdgcn_mfma_f32_16x16x32_bf16(af[mi], bfv[ni],
                                                              acc[mi][ni], 0, 0, 0);
  }

  // epilogue: C/D layout col = lane&15, row = (lane>>4)*4 + reg
  #pragma unroll
  for (int ni = 0; ni < 4; ni++) {
    int n = n0 + wn + ni * 16 + fr;
    float bv = bias[n];
    #pragma unroll
    for (int mi = 0; mi < 4; mi++) {
      int mbase = m0 + wm + mi * 16 + fq * 4;
      if (EPI == 3) {
        int b = mbase >> 12, l = mbase & 4095;
        size_t o = ((size_t)(b * 512 + n) << 12) + l;
        float4 xr = *reinterpret_cast<const float4*>(&((const float*)res)[o]);
        float4 vv;
        vv.x = acc[mi][ni][0] + bv + xr.x;
        vv.y = acc[mi][ni][1] + bv + xr.y;
        vv.z = acc[mi][ni][2] + bv + xr.z;
        vv.w = acc[mi][ni][3] + bv + xr.w;
        *reinterpret_cast<float4*>(&((float*)Cv)[o]) = vv;
      } else {
        #pragma unroll
        for (int r = 0; r < 4; r++) {
          size_t idx = (size_t)(mbase + r) * N + n;
          float v = acc[mi][ni][r] + bv;
          if (EPI == 1) {
            float rv;
            if constexpr (sizeof(TRES) == 2) rv = b2f(((const bf16*)res)[idx]);
            else                             rv = ((const float*)res)[idx];
            v += rv;
          }
          if constexpr (sizeof(TOUT) == 2) ((bf16*)Cv)[idx] = f2b(v);
          else                             ((float*)Cv)[idx] = v;
        }
      }
    }
  }
}

// ---------------- fused GEGLU GEMM: ffin = (hn@Wa+ba) * gelu(hn@Wg+bg) ----
// Wt is [4096][512]; rows [0,2048) = a-half, rows [2048,4096) = gate-half.
__global__ __launch_bounds__(256) void gemm_geglu(const bf16* __restrict__ A,
    const bf16* __restrict__ Wt, const float* __restrict__ bias,
    bf16* __restrict__ Cv, int K)
{
  __shared__ alignas(16) bf16 As[128 * 32];
  __shared__ alignas(16) bf16 Ba[128 * 32];
  __shared__ alignas(16) bf16 Bg[128 * 32];
  const int tid = threadIdx.x;
  const int m0 = blockIdx.y * 128;
  const int n0 = blockIdx.x * 128;
  const int lane = tid & 63;
  const int wave = tid >> 6;
  const int wm = (wave >> 1) * 64;
  const int wn = (wave & 1) * 64;
  const int fr = lane & 15;
  const int fq = lane >> 4;
  const int srow = wave * 32 + (lane >> 2);
  const int scol = (lane & 3) * 8;

  const bf16* ga0 = A  + (size_t)(m0 + srow) * K + scol;
  const bf16* ga1 = ga0 + (size_t)16 * K;
  const bf16* gba0 = Wt + (size_t)(n0 + srow) * K + scol;
  const bf16* gba1 = gba0 + (size_t)16 * K;
  const bf16* gbg0 = Wt + (size_t)(2048 + n0 + srow) * K + scol;
  const bf16* gbg1 = gbg0 + (size_t)16 * K;
  bf16* la0 = &As[wave * 32 * 32]; bf16* la1 = la0 + 16 * 32;
  bf16* lba0 = &Ba[wave * 32 * 32]; bf16* lba1 = lba0 + 16 * 32;
  bf16* lbg0 = &Bg[wave * 32 * 32]; bf16* lbg1 = lbg0 + 16 * 32;

  f32x4 aca[4][4], acg[4][4];
  #pragma unroll
  for (int i = 0; i < 4; i++)
    #pragma unroll
    for (int j = 0; j < 4; j++) {
      aca[i][j] = (f32x4){0.f, 0.f, 0.f, 0.f};
      acg[i][j] = (f32x4){0.f, 0.f, 0.f, 0.f};
    }

  for (int kt = 0; kt < K; kt += 32) {
    __syncthreads();
    gl_lds16(ga0, la0);  gl_lds16(ga1, la1);
    gl_lds16(gba0, lba0); gl_lds16(gba1, lba1);
    gl_lds16(gbg0, lbg0); gl_lds16(gbg1, lbg1);
    ga0 += 32; ga1 += 32; gba0 += 32; gba1 += 32; gbg0 += 32; gbg1 += 32;
    __syncthreads();
    short8 af[4], bav[4], bgv[4];
    #pragma unroll
    for (int mi = 0; mi < 4; mi++)
      af[mi] = *reinterpret_cast<const short8*>(&As[(wm + mi * 16 + fr) * 32 + fq * 8]);
    #pragma unroll
    for (int ni = 0; ni < 4; ni++) {
      bav[ni] = *reinterpret_cast<const short8*>(&Ba[(wn + ni * 16 + fr) * 32 + fq * 8]);
      bgv[ni] = *reinterpret_cast<const short8*>(&Bg[(wn + ni * 16 + fr) * 32 + fq * 8]);
    }
    #pragma unroll
    for (int mi = 0; mi < 4; mi++)
      #pragma unroll
      for (int ni = 0; ni < 4; ni++) {
        aca[mi][ni] = __builtin_amdgcn_mfma_f32_16x16x32_bf16(af[mi], bav[ni],
                                                              aca[mi][ni], 0, 0, 0);
        acg[mi][ni] = __builtin_amdgcn_mfma_f32_16x16x32_bf16(af[mi], bgv[ni],
                                                              acg[mi][ni], 0, 0, 0);
      }
  }

  #pragma unroll
  for (int ni = 0; ni < 4; ni++) {
    int n = n0 + wn + ni * 16 + fr;
    float bva = bias[n];
    float bvg = bias[2048 + n];
    #pragma unroll
    for (int mi = 0; mi < 4; mi++) {
      int mbase = m0 + wm + mi * 16 + fq * 4;
      #pragma unroll
      for (int r = 0; r < 4; r++) {
        size_t idx = (size_t)(mbase + r) * 2048 + n;
        float a = aca[mi][ni][r] + bva;
        float g = acg[mi][ni][r] + bvg;
        float v = a * (0.5f * g * (1.f + erff(g * 0.70710678118654752f)));
        Cv[idx] = f2b(v);
      }
    }
  }
}

// ---------------- MSDA: degenerate deformable attention (Hl=L, Wl=1) ------
// sa: [M][256] fp32: cols 0..127 = sampling offsets, 128..191 = attn logits
__global__ __launch_bounds__(256) void msda_k(const float* __restrict__ sa,
    const bf16* __restrict__ v2, bf16* __restrict__ outp)
{
  int unit = blockIdx.x * 4 + (threadIdx.x >> 6);  // (b*L+l)*8 + h
  int lane = threadIdx.x & 63;
  int m = unit >> 3;
  int h = unit & 7;
  int b = m >> 12;                                  // L = 4096
  const float* lg = &sa[(size_t)m * 256 + 128 + h * 8];
  float w[8], mx = -1e30f;
  #pragma unroll
  for (int p = 0; p < 8; p++) { w[p] = lg[p]; mx = fmaxf(mx, w[p]); }
  float sum = 0.f;
  #pragma unroll
  for (int p = 0; p < 8; p++) { w[p] = expf(w[p] - mx); sum += w[p]; }
  float rs = 1.f / sum;
  const float* op = &sa[(size_t)m * 256 + h * 16];
  size_t vbase = ((size_t)b * 4096) * 512 + h * 64 + lane;
  float acc = 0.f;
  #pragma unroll
  for (int p = 0; p < 8; p++) {
    float ox = op[p * 2 + 0], oy = op[p * 2 + 1];
    float gx = 2.f * (0.5f + ox) - 1.f;
    float px = ((gx + 1.f) * 1.f - 1.f) * 0.5f;              // = ox (mirrors ref fp ops)
    float gy = 2.f * (0.5f + oy * (1.f / 4096.f)) - 1.f;
    float py = ((gy + 1.f) * 4096.f - 1.f) * 0.5f;           // = oy + 2047.5
    float x0 = floorf(px), y0 = floorf(py);
    float lx = px - x0, ly = py - y0;
    int xi = (int)x0;
    int yi = (int)y0;
    float wx = (xi == 0) ? (1.f - lx) : ((xi == -1) ? lx : 0.f);
    if (wx != 0.f) {                         // wave-uniform branch
      float s = 0.f;
      if (yi >= 0 && yi < 4096)  s += (1.f - ly) * b2f(v2[vbase + (size_t)yi * 512]);
      if (yi >= -1 && yi < 4095) s += ly * b2f(v2[vbase + (size_t)(yi + 1) * 512]);
      acc += w[p] * rs * wx * s;
    }
  }
  outp[(size_t)m * 512 + h * 64 + lane] = f2b(acc);
}

// =========================================================================
extern "C" void kernel_launch(void* const* d_in, const int* in_sizes, int n_in,
                              void* d_out, int out_size, void* d_ws, size_t ws_size,
                              hipStream_t stream)
{
  if (n_in < 27) return;
  const float* x       = (const float*)d_in[0];
  const float* gn_g    = (const float*)d_in[1];
  const float* gn_b    = (const float*)d_in[2];
  const float* pin_w   = (const float*)d_in[3];
  const float* pin_b   = (const float*)d_in[4];
  const float* ln1_g   = (const float*)d_in[5];
  const float* ln1_b   = (const float*)d_in[6];
  const float* vproj_w = (const float*)d_in[7];
  const float* vproj_b = (const float*)d_in[8];
  const float* mvp_w   = (const float*)d_in[9];
  const float* mvp_b   = (const float*)d_in[10];
  const float* soff_w  = (const float*)d_in[11];
  const float* soff_b  = (const float*)d_in[12];
  const float* attw_w  = (const float*)d_in[13];
  const float* attw_b  = (const float*)d_in[14];
  const float* mop_w   = (const float*)d_in[15];
  const float* mop_b   = (const float*)d_in[16];
  const float* dout_w  = (const float*)d_in[17];
  const float* dout_b  = (const float*)d_in[18];
  const float* ln3_g   = (const float*)d_in[19];
  const float* ln3_b   = (const float*)d_in[20];
  const float* geglu_w = (const float*)d_in[21];
  const float* geglu_b = (const float*)d_in[22];
  const float* dense_w = (const float*)d_in[23];
  const float* dense_b = (const float*)d_in[24];
  const float* pout_w  = (const float*)d_in[25];
  const float* pout_b  = (const float*)d_in[26];
  float* out = (float*)d_out;

  char* ws = (char*)d_ws;
  size_t off = 0;
  auto alloc = [&](size_t bytes) -> char* {
    off = (off + 255) & ~(size_t)255;
    char* p = ws + off;
    off += bytes;
    return p;
  };
  // persistent weights (bf16, transposed)
  bf16* wtPin   = (bf16*)alloc(512 * 512 * 2);
  bf16* wtVproj = (bf16*)alloc(512 * 512 * 2);
  bf16* wtMvp   = (bf16*)alloc(512 * 512 * 2);
  bf16* wtMop   = (bf16*)alloc(512 * 512 * 2);
  bf16* wtDout  = (bf16*)alloc(512 * 512 * 2);
  bf16* wtPout  = (bf16*)alloc(512 * 512 * 2);
  bf16* wtSA    = (bf16*)alloc(256 * 512 * 2);     // [soff 128 | attw 64 | pad 64]
  bf16* wtGeglu = (bf16*)alloc((size_t)4096 * 512 * 2);
  bf16* wtDense = (bf16*)alloc((size_t)512 * 2048 * 2);
  float* biasSA = (float*)alloc(256 * 4);
  float* stats  = (float*)alloc(64 * 4);
  // activation regions with liveness-checked unions
  char* A  = alloc(32 * MB);  // t32 (early) | hn@0 (16MB) + t3@16MB
  char* Cg = alloc(32 * MB);  // t2 (fp32)
  char* D  = alloc(64 * MB);  // xnt@0, v@16, v2@32, msda@48
  char* E  = alloc(64 * MB);  // q16@0, sa32@16 (16MB), m2@32 (16MB) | ffin@0 (64MB)
  if (off > ws_size) return;  // workspace too small — fail loudly (zero output)

  float* t32   = (float*)A;
  bf16*  hn    = (bf16*)A;
  bf16*  t3    = (bf16*)(A + 16 * MB);
  float* t2    = (float*)Cg;
  bf16*  xnt   = (bf16*)D;
  bf16*  v16   = (bf16*)(D + 16 * MB);
  bf16*  v2b   = (bf16*)(D + 32 * MB);
  bf16*  msda  = (bf16*)(D + 48 * MB);
  bf16*  q16   = (bf16*)E;
  float* sa32  = (float*)(E + 16 * MB);
  bf16*  m2    = (bf16*)(E + 32 * MB);
  bf16*  ffin  = (bf16*)E;

  hipMemsetAsync(stats, 0, 64 * 4, stream);
  pack_bias_sa<<<1, 256, 0, stream>>>(soff_b, attw_b, biasSA);

  dim3 tb(32, 8);
  transpose_pad<<<dim3(16, 16),  tb, 0, stream>>>(pin_w,   wtPin,   512, 512, 512);
  transpose_pad<<<dim3(16, 16),  tb, 0, stream>>>(vproj_w, wtVproj, 512, 512, 512);
  transpose_pad<<<dim3(16, 16),  tb, 0, stream>>>(mvp_w,   wtMvp,   512, 512, 512);
  transpose_pad<<<dim3(16, 16),  tb, 0, stream>>>(mop_w,   wtMop,   512, 512, 512);
  transpose_pad<<<dim3(16, 16),  tb, 0, stream>>>(dout_w,  wtDout,  512, 512, 512);
  transpose_pad<<<dim3(16, 16),  tb, 0, stream>>>(pout_w,  wtPout,  512, 512, 512);
  transpose_pad<<<dim3(16, 4),   tb, 0, stream>>>(soff_w,  wtSA,            512, 128, 128);
  transpose_pad<<<dim3(16, 4),   tb, 0, stream>>>(attw_w,  wtSA + 128 * 512, 512,  64, 128);
  transpose_pad<<<dim3(16, 128), tb, 0, stream>>>(geglu_w, wtGeglu, 512, 4096, 4096);
  transpose_pad<<<dim3(64, 16),  tb, 0, stream>>>(dense_w, wtDense, 2048, 512, 512);

  gn_partial<<<512, 256, 0, stream>>>(x, stats);
  gn_apply_t<<<dim3(128, 16, 4), tb, 0, stream>>>(x, stats, gn_g, gn_b, xnt);

  // t = xnt @ pin + b   (fp32 trunk)
  gemm_bt<float, float, 0><<<dim3(4, 128), 256, 0, stream>>>(
      xnt, wtPin, pin_b, nullptr, t32, M_, 512, 512);
  // q = LN1(t)
  layernorm_k<<<4096, 256, 0, stream>>>(t32, ln1_g, ln1_b, q16);
  // value = q @ vproj ; v2 = value @ mvp
  gemm_bt<bf16, float, 0><<<dim3(4, 128), 256, 0, stream>>>(
      q16, wtVproj, vproj_b, nullptr, v16, M_, 512, 512);
  gemm_bt<bf16, float, 0><<<dim3(4, 128), 256, 0, stream>>>(
      v16, wtMvp, mvp_b, nullptr, v2b, M_, 512, 512);
  // combined sampling offsets + attention logits (fp32 out, N=256)
  gemm_bt<float, float, 0><<<dim3(2, 128), 256, 0, stream>>>(
      q16, wtSA, biasSA, nullptr, sa32, M_, 256, 512);
  msda_k<<<32768, 256, 0, stream>>>(sa32, v2b, msda);
  // m2 = msda @ mop + b + q ; t2 = m2 @ dout + b + t (fp32 trunk)
  gemm_bt<bf16, bf16, 1><<<dim3(4, 128), 256, 0, stream>>>(
      msda, wtMop, mop_b, q16, m2, M_, 512, 512);
  gemm_bt<float, float, 1><<<dim3(4, 128), 256, 0, stream>>>(
      m2, wtDout, dout_b, t32, t2, M_, 512, 512);
  // hn = LN3(t2)
  layernorm_k<<<4096, 256, 0, stream>>>(t2, ln3_g, ln3_b, hn);
  // ffin = (hn @ Wa + ba) * gelu(hn @ Wg + bg)   — fused GEGLU
  gemm_geglu<<<dim3(16, 128), 256, 0, stream>>>(hn, wtGeglu, geglu_b, ffin, 512);
  // t3 = ffin @ dense + b + t2
  gemm_bt<bf16, float, 1><<<dim3(4, 128), 256, 0, stream>>>(
      ffin, wtDense, dense_b, t2, t3, M_, 512, 2048);
  // out[b,c,l] = (t3 @ pout + b)[b,l,c] + x[b,c,l]   (fused transpose epilogue)
  gemm_bt<float, float, 3><<<dim3(4, 128), 256, 0, stream>>>(
      t3, wtPout, pout_b, x, out, M_, 512, 512);
}

// Round 4
// 621.714 us; speedup vs baseline: 1.0661x; 1.0661x over previous
//
#include <hip/hip_runtime.h>
#include <hip/hip_bf16.h>
#include <math.h>

using bf16 = __hip_bfloat16;
typedef __attribute__((ext_vector_type(8))) short short8;
typedef __attribute__((ext_vector_type(4))) float f32x4;

static constexpr int B_ = 4, C_ = 512, L_ = 4096, M_ = 16384;
static constexpr size_t MB = 1ull << 20;

__device__ __forceinline__ float b2f(bf16 v){ return __bfloat162float(v); }
__device__ __forceinline__ bf16  f2b(float v){ return __float2bfloat16(v); }

// async global -> LDS, 16B per lane, lane l lands at ldsbase + l*16
__device__ __forceinline__ void gl_lds16(const bf16* g, bf16* l) {
  __builtin_amdgcn_global_load_lds(
      (const __attribute__((address_space(1))) unsigned int*)g,
      (__attribute__((address_space(3))) unsigned int*)l, 16, 0, 0);
}

// gelu(g) = 0.5 g (1 + erf(g/sqrt2)); erf via A&S 7.1.26 (|eps| < 1.5e-7)
__device__ __forceinline__ float fast_gelu(float g) {
  float t  = g * 0.70710678118654752f;
  float at = fabsf(t);
  float k  = 1.f / (1.f + 0.3275911f * at);
  float poly = k * (0.254829592f + k * (-0.284496736f + k * (1.421413741f +
               k * (-1.453152027f + k * 1.061405429f))));
  float erfv = 1.f - poly * __expf(-at * at);
  erfv = __builtin_copysignf(erfv, t);
  return 0.5f * g * (1.f + erfv);
}

// ---------------- weight transpose fp32 -> bf16 (+ zero pad rows of Wt) ----
__global__ __launch_bounds__(256) void transpose_pad(const float* __restrict__ W,
    bf16* __restrict__ Wt, int K, int N, int Npad)
{
  __shared__ float tile[32][33];
  int k0 = blockIdx.x * 32, n0 = blockIdx.y * 32;
  int tx = threadIdx.x, ty = threadIdx.y;
  #pragma unroll
  for (int i = 0; i < 32; i += 8) {
    int k = k0 + ty + i, n = n0 + tx;
    tile[ty + i][tx] = (n < N) ? W[(size_t)k * N + n] : 0.f;
  }
  __syncthreads();
  #pragma unroll
  for (int i = 0; i < 32; i += 8) {
    int n = n0 + ty + i, k = k0 + tx;
    Wt[(size_t)n * K + k] = f2b(tile[tx][ty + i]);
  }
}

// combined bias for [soff(128) | attw(64) | zero(64)]
__global__ void pack_bias_sa(const float* __restrict__ sb,
                             const float* __restrict__ ab, float* __restrict__ bp){
  int i = threadIdx.x;           // 256 threads
  float v = 0.f;
  if (i < 128) v = sb[i]; else if (i < 192) v = ab[i - 128];
  bp[i] = v;
}

// ---------------- GroupNorm stats (sum, sumsq per (b,g)) ----------------
__global__ __launch_bounds__(256) void gn_partial(const float* __restrict__ x,
                                                  float* __restrict__ stats)
{
  int bg = blockIdx.x >> 4;
  int sc = blockIdx.x & 15;
  size_t base = (size_t)bg * 262144 + (size_t)sc * 16384;
  int tid = threadIdx.x;
  float s = 0.f, s2 = 0.f;
  #pragma unroll
  for (int i = 0; i < 8; i++) {
    size_t o = base + ((size_t)i * 256 + tid) * 8;
    float4 a = *reinterpret_cast<const float4*>(&x[o]);
    float4 b = *reinterpret_cast<const float4*>(&x[o + 4]);
    s  += a.x + a.y + a.z + a.w + b.x + b.y + b.z + b.w;
    s2 += a.x*a.x + a.y*a.y + a.z*a.z + a.w*a.w
        + b.x*b.x + b.y*b.y + b.z*b.z + b.w*b.w;
  }
  #pragma unroll
  for (int o = 32; o; o >>= 1) { s += __shfl_xor(s, o, 64); s2 += __shfl_xor(s2, o, 64); }
  __shared__ float ls[4], ls2[4];
  int wave = tid >> 6, lane = tid & 63;
  if (lane == 0) { ls[wave] = s; ls2[wave] = s2; }
  __syncthreads();
  if (tid == 0) {
    atomicAdd(&stats[bg * 2 + 0], ls[0] + ls[1] + ls[2] + ls[3]);
    atomicAdd(&stats[bg * 2 + 1], ls2[0] + ls2[1] + ls2[2] + ls2[3]);
  }
}

// ---------------- GN apply + transpose (B,C,L) -> (B*L, C) bf16 ----------
__global__ __launch_bounds__(256) void gn_apply_t(const float* __restrict__ x,
    const float* __restrict__ stats, const float* __restrict__ gg,
    const float* __restrict__ gb, bf16* __restrict__ xnt)
{
  __shared__ float tile[32][33];
  int b = blockIdx.z, c0 = blockIdx.y * 32, l0 = blockIdx.x * 32;
  int tx = threadIdx.x, ty = threadIdx.y;
  #pragma unroll
  for (int i = 0; i < 32; i += 8) {
    int c = c0 + ty + i, l = l0 + tx;
    int grp = b * 8 + (c >> 6);
    float sum = stats[grp * 2], ss = stats[grp * 2 + 1];
    float mu = sum * (1.f / 262144.f);
    float inv = rsqrtf(ss * (1.f / 262144.f) - mu * mu + 1e-5f);
    float v = x[((size_t)b * 512 + c) * 4096 + l];
    tile[ty + i][tx] = (v - mu) * inv * gg[c] + gb[c];
  }
  __syncthreads();
  #pragma unroll
  for (int i = 0; i < 32; i += 8) {
    int l = l0 + ty + i, c = c0 + tx;
    xnt[((size_t)b * 4096 + l) * 512 + c] = f2b(tile[tx][ty + i]);
  }
}

// ---------------- LayerNorm over C=512: fp32 in, bf16 out, 1 wave/row -----
__global__ __launch_bounds__(256) void layernorm_k(const float* __restrict__ X,
    const float* __restrict__ g, const float* __restrict__ b, bf16* __restrict__ Y)
{
  int row = blockIdx.x * 4 + (threadIdx.x >> 6);
  int lane = threadIdx.x & 63;
  const float* xr = X + (size_t)row * 512 + lane * 8;
  float4 a = *reinterpret_cast<const float4*>(xr);
  float4 c = *reinterpret_cast<const float4*>(xr + 4);
  float v[8] = {a.x, a.y, a.z, a.w, c.x, c.y, c.z, c.w};
  float s = 0.f, s2 = 0.f;
  #pragma unroll
  for (int i = 0; i < 8; i++) { s += v[i]; s2 += v[i] * v[i]; }
  #pragma unroll
  for (int o = 32; o; o >>= 1) { s += __shfl_xor(s, o, 64); s2 += __shfl_xor(s2, o, 64); }
  float mu = s * (1.f / 512.f);
  float inv = rsqrtf(s2 * (1.f / 512.f) - mu * mu + 1e-5f);
  float4 g0 = *reinterpret_cast<const float4*>(&g[lane * 8]);
  float4 g1 = *reinterpret_cast<const float4*>(&g[lane * 8 + 4]);
  float4 b0 = *reinterpret_cast<const float4*>(&b[lane * 8]);
  float4 b1 = *reinterpret_cast<const float4*>(&b[lane * 8 + 4]);
  float gv[8] = {g0.x, g0.y, g0.z, g0.w, g1.x, g1.y, g1.z, g1.w};
  float bv[8] = {b0.x, b0.y, b0.z, b0.w, b1.x, b1.y, b1.z, b1.w};
  bf16 outv[8];
  #pragma unroll
  for (int i = 0; i < 8; i++) outv[i] = f2b((v[i] - mu) * inv * gv[i] + bv[i]);
  *reinterpret_cast<uint4*>(Y + (size_t)row * 512 + lane * 8) =
      *reinterpret_cast<const uint4*>(outv);
}

// ---------------- MFMA GEMM, double-buffered async staging ----------------
// C[M,N] = A[M,K] * Bt[N,K]^T + bias (+epi)
// EPI: 0 none | 1 += res[idx] | 3 transpose+residual fp32 out
template<typename TOUT, typename TRES, int EPI>
__global__ __launch_bounds__(256) void gemm_bt(const bf16* __restrict__ A,
    const bf16* __restrict__ Bt, const float* __restrict__ bias,
    const TRES* __restrict__ res, TOUT* __restrict__ Cv, int M, int N, int K)
{
  __shared__ alignas(16) bf16 As[2][128 * 32];
  __shared__ alignas(16) bf16 Bs[2][128 * 32];
  const int tid = threadIdx.x;
  const int m0 = blockIdx.y * 128;
  const int n0 = blockIdx.x * 128;
  const int lane = tid & 63;
  const int wave = tid >> 6;
  const int wm = (wave >> 1) * 64;
  const int wn = (wave & 1) * 64;
  const int fr = lane & 15;
  const int fq = lane >> 4;
  const int srow = wave * 32 + (lane >> 2);   // staged row for this lane
  const int scol = (lane & 3) * 8;            // bf16 col offset (16B granule)
  const int lofs = wave * 32 * 32;            // wave's LDS chunk within a buffer

  const bf16* gaBase = A  + (size_t)(m0 + srow) * K + scol;
  const bf16* gbBase = Bt + (size_t)(n0 + srow) * K + scol;

  f32x4 acc[4][4];
  #pragma unroll
  for (int i = 0; i < 4; i++)
    #pragma unroll
    for (int j = 0; j < 4; j++) acc[i][j] = (f32x4){0.f, 0.f, 0.f, 0.f};

  auto stage = [&](int buf, int kt) {
    const bf16* ga = gaBase + kt;
    const bf16* gb = gbBase + kt;
    bf16* la = &As[buf][lofs];
    bf16* lb = &Bs[buf][lofs];
    gl_lds16(ga, la);            gl_lds16(ga + (size_t)16 * K, la + 16 * 32);
    gl_lds16(gb, lb);            gl_lds16(gb + (size_t)16 * K, lb + 16 * 32);
  };

  stage(0, 0);
  int cur = 0;
  for (int kt = 0; kt < K; kt += 32) {
    __syncthreads();                       // drains stage(cur); frees buf cur^1
    if (kt + 32 < K) stage(cur ^ 1, kt + 32);   // async prefetch next tile
    short8 af[4], bfv[4];
    #pragma unroll
    for (int mi = 0; mi < 4; mi++)
      af[mi] = *reinterpret_cast<const short8*>(&As[cur][(wm + mi * 16 + fr) * 32 + fq * 8]);
    #pragma unroll
    for (int ni = 0; ni < 4; ni++)
      bfv[ni] = *reinterpret_cast<const short8*>(&Bs[cur][(wn + ni * 16 + fr) * 32 + fq * 8]);
    #pragma unroll
    for (int mi = 0; mi < 4; mi++)
      #pragma unroll
      for (int ni = 0; ni < 4; ni++)
        acc[mi][ni] = __builtin_amdgcn_mfma_f32_16x16x32_bf16(af[mi], bfv[ni],
                                                              acc[mi][ni], 0, 0, 0);
    cur ^= 1;
  }

  // epilogue: C/D layout col = lane&15, row = (lane>>4)*4 + reg
  #pragma unroll
  for (int ni = 0; ni < 4; ni++) {
    int n = n0 + wn + ni * 16 + fr;
    float bv = bias[n];
    #pragma unroll
    for (int mi = 0; mi < 4; mi++) {
      int mbase = m0 + wm + mi * 16 + fq * 4;
      if (EPI == 3) {
        int b = mbase >> 12, l = mbase & 4095;
        size_t o = ((size_t)(b * 512 + n) << 12) + l;
        float4 xr = *reinterpret_cast<const float4*>(&((const float*)res)[o]);
        float4 vv;
        vv.x = acc[mi][ni][0] + bv + xr.x;
        vv.y = acc[mi][ni][1] + bv + xr.y;
        vv.z = acc[mi][ni][2] + bv + xr.z;
        vv.w = acc[mi][ni][3] + bv + xr.w;
        *reinterpret_cast<float4*>(&((float*)Cv)[o]) = vv;
      } else {
        #pragma unroll
        for (int r = 0; r < 4; r++) {
          size_t idx = (size_t)(mbase + r) * N + n;
          float v = acc[mi][ni][r] + bv;
          if (EPI == 1) {
            float rv;
            if constexpr (sizeof(TRES) == 2) rv = b2f(((const bf16*)res)[idx]);
            else                             rv = ((const float*)res)[idx];
            v += rv;
          }
          if constexpr (sizeof(TOUT) == 2) ((bf16*)Cv)[idx] = f2b(v);
          else                             ((float*)Cv)[idx] = v;
        }
      }
    }
  }
}

// ---------------- fused GEGLU GEMM (dbuf): ffin = (hn@Wa+ba)*gelu(hn@Wg+bg)
// Wt is [4096][512]; rows [0,2048) = a-half, rows [2048,4096) = gate-half.
__global__ __launch_bounds__(256) void gemm_geglu(const bf16* __restrict__ A,
    const bf16* __restrict__ Wt, const float* __restrict__ bias,
    bf16* __restrict__ Cv, int K)
{
  __shared__ alignas(16) bf16 As[2][128 * 32];
  __shared__ alignas(16) bf16 Ba[2][128 * 32];
  __shared__ alignas(16) bf16 Bg[2][128 * 32];
  const int tid = threadIdx.x;
  const int m0 = blockIdx.y * 128;
  const int n0 = blockIdx.x * 128;
  const int lane = tid & 63;
  const int wave = tid >> 6;
  const int wm = (wave >> 1) * 64;
  const int wn = (wave & 1) * 64;
  const int fr = lane & 15;
  const int fq = lane >> 4;
  const int srow = wave * 32 + (lane >> 2);
  const int scol = (lane & 3) * 8;
  const int lofs = wave * 32 * 32;

  const bf16* gaBase  = A  + (size_t)(m0 + srow) * K + scol;
  const bf16* gbaBase = Wt + (size_t)(n0 + srow) * K + scol;
  const bf16* gbgBase = Wt + (size_t)(2048 + n0 + srow) * K + scol;

  f32x4 aca[4][4], acg[4][4];
  #pragma unroll
  for (int i = 0; i < 4; i++)
    #pragma unroll
    for (int j = 0; j < 4; j++) {
      aca[i][j] = (f32x4){0.f, 0.f, 0.f, 0.f};
      acg[i][j] = (f32x4){0.f, 0.f, 0.f, 0.f};
    }

  auto stage = [&](int buf, int kt) {
    const bf16* ga  = gaBase  + kt;
    const bf16* gba = gbaBase + kt;
    const bf16* gbg = gbgBase + kt;
    bf16* la  = &As[buf][lofs];
    bf16* lba = &Ba[buf][lofs];
    bf16* lbg = &Bg[buf][lofs];
    gl_lds16(ga,  la);   gl_lds16(ga  + (size_t)16 * K, la  + 16 * 32);
    gl_lds16(gba, lba);  gl_lds16(gba + (size_t)16 * K, lba + 16 * 32);
    gl_lds16(gbg, lbg);  gl_lds16(gbg + (size_t)16 * K, lbg + 16 * 32);
  };

  stage(0, 0);
  int cur = 0;
  for (int kt = 0; kt < K; kt += 32) {
    __syncthreads();
    if (kt + 32 < K) stage(cur ^ 1, kt + 32);
    short8 af[4], bav[4], bgv[4];
    #pragma unroll
    for (int mi = 0; mi < 4; mi++)
      af[mi] = *reinterpret_cast<const short8*>(&As[cur][(wm + mi * 16 + fr) * 32 + fq * 8]);
    #pragma unroll
    for (int ni = 0; ni < 4; ni++) {
      bav[ni] = *reinterpret_cast<const short8*>(&Ba[cur][(wn + ni * 16 + fr) * 32 + fq * 8]);
      bgv[ni] = *reinterpret_cast<const short8*>(&Bg[cur][(wn + ni * 16 + fr) * 32 + fq * 8]);
    }
    #pragma unroll
    for (int mi = 0; mi < 4; mi++)
      #pragma unroll
      for (int ni = 0; ni < 4; ni++) {
        aca[mi][ni] = __builtin_amdgcn_mfma_f32_16x16x32_bf16(af[mi], bav[ni],
                                                              aca[mi][ni], 0, 0, 0);
        acg[mi][ni] = __builtin_amdgcn_mfma_f32_16x16x32_bf16(af[mi], bgv[ni],
                                                              acg[mi][ni], 0, 0, 0);
      }
    cur ^= 1;
  }

  #pragma unroll
  for (int ni = 0; ni < 4; ni++) {
    int n = n0 + wn + ni * 16 + fr;
    float bva = bias[n];
    float bvg = bias[2048 + n];
    #pragma unroll
    for (int mi = 0; mi < 4; mi++) {
      int mbase = m0 + wm + mi * 16 + fq * 4;
      #pragma unroll
      for (int r = 0; r < 4; r++) {
        size_t idx = (size_t)(mbase + r) * 2048 + n;
        float a = aca[mi][ni][r] + bva;
        float g = acg[mi][ni][r] + bvg;
        Cv[idx] = f2b(a * fast_gelu(g));
      }
    }
  }
}

// ---------------- MSDA: degenerate deformable attention (Hl=L, Wl=1) ------
// sa: [M][256] fp32: cols 0..127 = sampling offsets, 128..191 = attn logits
__global__ __launch_bounds__(256) void msda_k(const float* __restrict__ sa,
    const bf16* __restrict__ v2, bf16* __restrict__ outp)
{
  int unit = blockIdx.x * 4 + (threadIdx.x >> 6);  // (b*L+l)*8 + h
  int lane = threadIdx.x & 63;
  int m = unit >> 3;
  int h = unit & 7;
  int b = m >> 12;                                  // L = 4096
  const float* lg = &sa[(size_t)m * 256 + 128 + h * 8];
  float w[8], mx = -1e30f;
  #pragma unroll
  for (int p = 0; p < 8; p++) { w[p] = lg[p]; mx = fmaxf(mx, w[p]); }
  float sum = 0.f;
  #pragma unroll
  for (int p = 0; p < 8; p++) { w[p] = expf(w[p] - mx); sum += w[p]; }
  float rs = 1.f / sum;
  const float* op = &sa[(size_t)m * 256 + h * 16];
  size_t vbase = ((size_t)b * 4096) * 512 + h * 64 + lane;
  float acc = 0.f;
  #pragma unroll
  for (int p = 0; p < 8; p++) {
    float ox = op[p * 2 + 0], oy = op[p * 2 + 1];
    float gx = 2.f * (0.5f + ox) - 1.f;
    float px = ((gx + 1.f) * 1.f - 1.f) * 0.5f;              // = ox (mirrors ref fp ops)
    float gy = 2.f * (0.5f + oy * (1.f / 4096.f)) - 1.f;
    float py = ((gy + 1.f) * 4096.f - 1.f) * 0.5f;           // = oy + 2047.5
    float x0 = floorf(px), y0 = floorf(py);
    float lx = px - x0, ly = py - y0;
    int xi = (int)x0;
    int yi = (int)y0;
    float wx = (xi == 0) ? (1.f - lx) : ((xi == -1) ? lx : 0.f);
    if (wx != 0.f) {                         // wave-uniform branch
      float s = 0.f;
      if (yi >= 0 && yi < 4096)  s += (1.f - ly) * b2f(v2[vbase + (size_t)yi * 512]);
      if (yi >= -1 && yi < 4095) s += ly * b2f(v2[vbase + (size_t)(yi + 1) * 512]);
      acc += w[p] * rs * wx * s;
    }
  }
  outp[(size_t)m * 512 + h * 64 + lane] = f2b(acc);
}

// =========================================================================
extern "C" void kernel_launch(void* const* d_in, const int* in_sizes, int n_in,
                              void* d_out, int out_size, void* d_ws, size_t ws_size,
                              hipStream_t stream)
{
  if (n_in < 27) return;
  const float* x       = (const float*)d_in[0];
  const float* gn_g    = (const float*)d_in[1];
  const float* gn_b    = (const float*)d_in[2];
  const float* pin_w   = (const float*)d_in[3];
  const float* pin_b   = (const float*)d_in[4];
  const float* ln1_g   = (const float*)d_in[5];
  const float* ln1_b   = (const float*)d_in[6];
  const float* vproj_w = (const float*)d_in[7];
  const float* vproj_b = (const float*)d_in[8];
  const float* mvp_w   = (const float*)d_in[9];
  const float* mvp_b   = (const float*)d_in[10];
  const float* soff_w  = (const float*)d_in[11];
  const float* soff_b  = (const float*)d_in[12];
  const float* attw_w  = (const float*)d_in[13];
  const float* attw_b  = (const float*)d_in[14];
  const float* mop_w   = (const float*)d_in[15];
  const float* mop_b   = (const float*)d_in[16];
  const float* dout_w  = (const float*)d_in[17];
  const float* dout_b  = (const float*)d_in[18];
  const float* ln3_g   = (const float*)d_in[19];
  const float* ln3_b   = (const float*)d_in[20];
  const float* geglu_w = (const float*)d_in[21];
  const float* geglu_b = (const float*)d_in[22];
  const float* dense_w = (const float*)d_in[23];
  const float* dense_b = (const float*)d_in[24];
  const float* pout_w  = (const float*)d_in[25];
  const float* pout_b  = (const float*)d_in[26];
  float* out = (float*)d_out;

  char* ws = (char*)d_ws;
  size_t off = 0;
  auto alloc = [&](size_t bytes) -> char* {
    off = (off + 255) & ~(size_t)255;
    char* p = ws + off;
    off += bytes;
    return p;
  };
  // persistent weights (bf16, transposed)
  bf16* wtPin   = (bf16*)alloc(512 * 512 * 2);
  bf16* wtVproj = (bf16*)alloc(512 * 512 * 2);
  bf16* wtMvp   = (bf16*)alloc(512 * 512 * 2);
  bf16* wtMop   = (bf16*)alloc(512 * 512 * 2);
  bf16* wtDout  = (bf16*)alloc(512 * 512 * 2);
  bf16* wtPout  = (bf16*)alloc(512 * 512 * 2);
  bf16* wtSA    = (bf16*)alloc(256 * 512 * 2);     // [soff 128 | attw 64 | pad 64]
  bf16* wtGeglu = (bf16*)alloc((size_t)4096 * 512 * 2);
  bf16* wtDense = (bf16*)alloc((size_t)512 * 2048 * 2);
  float* biasSA = (float*)alloc(256 * 4);
  float* stats  = (float*)alloc(64 * 4);
  // activation regions with liveness-checked unions
  char* A  = alloc(32 * MB);  // t32 (early) | hn@0 (16MB) + t3@16MB
  char* Cg = alloc(32 * MB);  // t2 (fp32)
  char* D  = alloc(64 * MB);  // xnt@0, v@16, v2@32, msda@48
  char* E  = alloc(64 * MB);  // q16@0, sa32@16 (16MB), m2@32 (16MB) | ffin@0 (64MB)
  if (off > ws_size) return;  // workspace too small — fail loudly (zero output)

  float* t32   = (float*)A;
  bf16*  hn    = (bf16*)A;
  bf16*  t3    = (bf16*)(A + 16 * MB);
  float* t2    = (float*)Cg;
  bf16*  xnt   = (bf16*)D;
  bf16*  v16   = (bf16*)(D + 16 * MB);
  bf16*  v2b   = (bf16*)(D + 32 * MB);
  bf16*  msda  = (bf16*)(D + 48 * MB);
  bf16*  q16   = (bf16*)E;
  float* sa32  = (float*)(E + 16 * MB);
  bf16*  m2    = (bf16*)(E + 32 * MB);
  bf16*  ffin  = (bf16*)E;

  hipMemsetAsync(stats, 0, 64 * 4, stream);
  pack_bias_sa<<<1, 256, 0, stream>>>(soff_b, attw_b, biasSA);

  dim3 tb(32, 8);
  transpose_pad<<<dim3(16, 16),  tb, 0, stream>>>(pin_w,   wtPin,   512, 512, 512);
  transpose_pad<<<dim3(16, 16),  tb, 0, stream>>>(vproj_w, wtVproj, 512, 512, 512);
  transpose_pad<<<dim3(16, 16),  tb, 0, stream>>>(mvp_w,   wtMvp,   512, 512, 512);
  transpose_pad<<<dim3(16, 16),  tb, 0, stream>>>(mop_w,   wtMop,   512, 512, 512);
  transpose_pad<<<dim3(16, 16),  tb, 0, stream>>>(dout_w,  wtDout,  512, 512, 512);
  transpose_pad<<<dim3(16, 16),  tb, 0, stream>>>(pout_w,  wtPout,  512, 512, 512);
  transpose_pad<<<dim3(16, 4),   tb, 0, stream>>>(soff_w,  wtSA,            512, 128, 128);
  transpose_pad<<<dim3(16, 4),   tb, 0, stream>>>(attw_w,  wtSA + 128 * 512, 512,  64, 128);
  transpose_pad<<<dim3(16, 128), tb, 0, stream>>>(geglu_w, wtGeglu, 512, 4096, 4096);
  transpose_pad<<<dim3(64, 16),  tb, 0, stream>>>(dense_w, wtDense, 2048, 512, 512);

  gn_partial<<<512, 256, 0, stream>>>(x, stats);
  gn_apply_t<<<dim3(128, 16, 4), tb, 0, stream>>>(x, stats, gn_g, gn_b, xnt);

  // t = xnt @ pin + b   (fp32 trunk)
  gemm_bt<float, float, 0><<<dim3(4, 128), 256, 0, stream>>>(
      xnt, wtPin, pin_b, nullptr, t32, M_, 512, 512);
  // q = LN1(t)
  layernorm_k<<<4096, 256, 0, stream>>>(t32, ln1_g, ln1_b, q16);
  // value = q @ vproj ; v2 = value @ mvp
  gemm_bt<bf16, float, 0><<<dim3(4, 128), 256, 0, stream>>>(
      q16, wtVproj, vproj_b, nullptr, v16, M_, 512, 512);
  gemm_bt<bf16, float, 0><<<dim3(4, 128), 256, 0, stream>>>(
      v16, wtMvp, mvp_b, nullptr, v2b, M_, 512, 512);
  // combined sampling offsets + attention logits (fp32 out, N=256)
  gemm_bt<float, float, 0><<<dim3(2, 128), 256, 0, stream>>>(
      q16, wtSA, biasSA, nullptr, sa32, M_, 256, 512);
  msda_k<<<32768, 256, 0, stream>>>(sa32, v2b, msda);
  // m2 = msda @ mop + b + q ; t2 = m2 @ dout + b + t (fp32 trunk)
  gemm_bt<bf16, bf16, 1><<<dim3(4, 128), 256, 0, stream>>>(
      msda, wtMop, mop_b, q16, m2, M_, 512, 512);
  gemm_bt<float, float, 1><<<dim3(4, 128), 256, 0, stream>>>(
      m2, wtDout, dout_b, t32, t2, M_, 512, 512);
  // hn = LN3(t2)
  layernorm_k<<<4096, 256, 0, stream>>>(t2, ln3_g, ln3_b, hn);
  // ffin = (hn @ Wa + ba) * gelu(hn @ Wg + bg)   — fused GEGLU
  gemm_geglu<<<dim3(16, 128), 256, 0, stream>>>(hn, wtGeglu, geglu_b, ffin, 512);
  // t3 = ffin @ dense + b + t2
  gemm_bt<bf16, float, 1><<<dim3(4, 128), 256, 0, stream>>>(
      ffin, wtDense, dense_b, t2, t3, M_, 512, 2048);
  // out[b,c,l] = (t3 @ pout + b)[b,l,c] + x[b,c,l]   (fused transpose epilogue)
  gemm_bt<float, float, 3><<<dim3(4, 128), 256, 0, stream>>>(
      t3, wtPout, pout_b, x, out, M_, 512, 512);
}

// Round 5
// 598.092 us; speedup vs baseline: 1.1082x; 1.0395x over previous
//
#include <hip/hip_runtime.h>
#include <hip/hip_bf16.h>
#include <math.h>

using bf16 = __hip_bfloat16;
typedef __attribute__((ext_vector_type(8))) short short8;
typedef __attribute__((ext_vector_type(4))) float f32x4;

static constexpr int B_ = 4, C_ = 512, L_ = 4096, M_ = 16384;
static constexpr size_t MB = 1ull << 20;

__device__ __forceinline__ float b2f(bf16 v){ return __bfloat162float(v); }
__device__ __forceinline__ bf16  f2b(float v){ return __float2bfloat16(v); }

// async global -> LDS, 16B per lane, lane l lands at ldsbase + l*16
__device__ __forceinline__ void gl_lds16(const bf16* g, bf16* l) {
  __builtin_amdgcn_global_load_lds(
      (const __attribute__((address_space(1))) unsigned int*)g,
      (__attribute__((address_space(3))) unsigned int*)l, 16, 0, 0);
}

// gelu(g) = 0.5 g (1 + erf(g/sqrt2)); erf via A&S 7.1.26 (|eps| < 1.5e-7)
__device__ __forceinline__ float fast_gelu(float g) {
  float t  = g * 0.70710678118654752f;
  float at = fabsf(t);
  float k  = 1.f / (1.f + 0.3275911f * at);
  float poly = k * (0.254829592f + k * (-0.284496736f + k * (1.421413741f +
               k * (-1.453152027f + k * 1.061405429f))));
  float erfv = 1.f - poly * __expf(-at * at);
  erfv = __builtin_copysignf(erfv, t);
  return 0.5f * g * (1.f + erfv);
}

// ---------------- fused weight transpose: 11 jobs in one dispatch ----------
// dst row = a*n + b (supports geglu interleave); cols >= N zero-padded.
struct TransJobs {
  const float* src[11];
  bf16* dst[11];
  int K[11], N[11], srcStride[11], srcColOff[11], a[11], b[11];
  int tileStart[12];
};

__global__ __launch_bounds__(256) void transpose_all(TransJobs J)
{
  __shared__ float tile[32][33];
  int t = blockIdx.x;
  int j = 0;
  #pragma unroll
  for (int q = 0; q < 10; q++) if (t >= J.tileStart[q + 1]) j = q + 1;
  t -= J.tileStart[j];
  const int kTiles = J.K[j] >> 5;
  const int k0 = (t % kTiles) * 32, n0 = (t / kTiles) * 32;
  const int tx = threadIdx.x, ty = threadIdx.y;
  const float* src = J.src[j];
  const int N = J.N[j], ss = J.srcStride[j], sc = J.srcColOff[j];
  #pragma unroll
  for (int i = 0; i < 32; i += 8) {
    int k = k0 + ty + i, n = n0 + tx;
    tile[ty + i][tx] = (n < N) ? src[(size_t)k * ss + sc + n] : 0.f;
  }
  __syncthreads();
  bf16* dst = J.dst[j];
  const int a = J.a[j], b = J.b[j], K = J.K[j];
  #pragma unroll
  for (int i = 0; i < 32; i += 8) {
    int n = n0 + ty + i, k = k0 + tx;
    dst[(size_t)(a * n + b) * K + k] = f2b(tile[tx][ty + i]);
  }
}

// combined bias [vproj(512) | soff(128) | attw(64) | zero(64)]
__global__ void pack_bias_big(const float* __restrict__ vb,
    const float* __restrict__ sb, const float* __restrict__ ab,
    float* __restrict__ bp){
  int i = blockIdx.x * 256 + threadIdx.x;   // 768 threads
  float v = 0.f;
  if (i < 512) v = vb[i];
  else if (i < 640) v = sb[i - 512];
  else if (i < 704) v = ab[i - 640];
  bp[i] = v;
}

// ---------------- GroupNorm stats (sum, sumsq per (b,g)) ----------------
__global__ __launch_bounds__(256) void gn_partial(const float* __restrict__ x,
                                                  float* __restrict__ stats)
{
  int bg = blockIdx.x >> 4;
  int sc = blockIdx.x & 15;
  size_t base = (size_t)bg * 262144 + (size_t)sc * 16384;
  int tid = threadIdx.x;
  float s = 0.f, s2 = 0.f;
  #pragma unroll
  for (int i = 0; i < 8; i++) {
    size_t o = base + ((size_t)i * 256 + tid) * 8;
    float4 a = *reinterpret_cast<const float4*>(&x[o]);
    float4 b = *reinterpret_cast<const float4*>(&x[o + 4]);
    s  += a.x + a.y + a.z + a.w + b.x + b.y + b.z + b.w;
    s2 += a.x*a.x + a.y*a.y + a.z*a.z + a.w*a.w
        + b.x*b.x + b.y*b.y + b.z*b.z + b.w*b.w;
  }
  #pragma unroll
  for (int o = 32; o; o >>= 1) { s += __shfl_xor(s, o, 64); s2 += __shfl_xor(s2, o, 64); }
  __shared__ float ls[4], ls2[4];
  int wave = tid >> 6, lane = tid & 63;
  if (lane == 0) { ls[wave] = s; ls2[wave] = s2; }
  __syncthreads();
  if (tid == 0) {
    atomicAdd(&stats[bg * 2 + 0], ls[0] + ls[1] + ls[2] + ls[3]);
    atomicAdd(&stats[bg * 2 + 1], ls2[0] + ls2[1] + ls2[2] + ls2[3]);
  }
}

// ---------------- GN apply + transpose (B,C,L) -> (B*L, C) bf16 ----------
__global__ __launch_bounds__(256) void gn_apply_t(const float* __restrict__ x,
    const float* __restrict__ stats, const float* __restrict__ gg,
    const float* __restrict__ gb, bf16* __restrict__ xnt)
{
  __shared__ float tile[32][33];
  int b = blockIdx.z, c0 = blockIdx.y * 32, l0 = blockIdx.x * 32;
  int tx = threadIdx.x, ty = threadIdx.y;
  #pragma unroll
  for (int i = 0; i < 32; i += 8) {
    int c = c0 + ty + i, l = l0 + tx;
    int grp = b * 8 + (c >> 6);
    float sum = stats[grp * 2], ss = stats[grp * 2 + 1];
    float mu = sum * (1.f / 262144.f);
    float inv = rsqrtf(ss * (1.f / 262144.f) - mu * mu + 1e-5f);
    float v = x[((size_t)b * 512 + c) * 4096 + l];
    tile[ty + i][tx] = (v - mu) * inv * gg[c] + gb[c];
  }
  __syncthreads();
  #pragma unroll
  for (int i = 0; i < 32; i += 8) {
    int l = l0 + ty + i, c = c0 + tx;
    xnt[((size_t)b * 4096 + l) * 512 + c] = f2b(tile[tx][ty + i]);
  }
}

// ---------------- LayerNorm over C=512: fp32 in, bf16 out, 1 wave/row -----
__global__ __launch_bounds__(256) void layernorm_k(const float* __restrict__ X,
    const float* __restrict__ g, const float* __restrict__ b, bf16* __restrict__ Y)
{
  int row = blockIdx.x * 4 + (threadIdx.x >> 6);
  int lane = threadIdx.x & 63;
  const float* xr = X + (size_t)row * 512 + lane * 8;
  float4 a = *reinterpret_cast<const float4*>(xr);
  float4 c = *reinterpret_cast<const float4*>(xr + 4);
  float v[8] = {a.x, a.y, a.z, a.w, c.x, c.y, c.z, c.w};
  float s = 0.f, s2 = 0.f;
  #pragma unroll
  for (int i = 0; i < 8; i++) { s += v[i]; s2 += v[i] * v[i]; }
  #pragma unroll
  for (int o = 32; o; o >>= 1) { s += __shfl_xor(s, o, 64); s2 += __shfl_xor(s2, o, 64); }
  float mu = s * (1.f / 512.f);
  float inv = rsqrtf(s2 * (1.f / 512.f) - mu * mu + 1e-5f);
  float4 g0 = *reinterpret_cast<const float4*>(&g[lane * 8]);
  float4 g1 = *reinterpret_cast<const float4*>(&g[lane * 8 + 4]);
  float4 b0 = *reinterpret_cast<const float4*>(&b[lane * 8]);
  float4 b1 = *reinterpret_cast<const float4*>(&b[lane * 8 + 4]);
  float gv[8] = {g0.x, g0.y, g0.z, g0.w, g1.x, g1.y, g1.z, g1.w};
  float bv[8] = {b0.x, b0.y, b0.z, b0.w, b1.x, b1.y, b1.z, b1.w};
  bf16 outv[8];
  #pragma unroll
  for (int i = 0; i < 8; i++) outv[i] = f2b((v[i] - mu) * inv * gv[i] + bv[i]);
  *reinterpret_cast<uint4*>(Y + (size_t)row * 512 + lane * 8) =
      *reinterpret_cast<const uint4*>(outv);
}

// ---------------- MFMA GEMM, double-buffered async staging ----------------
// C[M,N] = A[M,K] * Bt[N,K]^T + bias (+epi)
// EPI: 0 none | 1 += res[idx] | 3 transpose+residual fp32 out
// EPI 4: vproj+SA split — n<512 -> bf16 Cv[m*512+n]; n>=512 -> fp32 res2[m*256+n-512]
template<typename TOUT, typename TRES, int EPI>
__global__ __launch_bounds__(256) void gemm_bt(const bf16* __restrict__ A,
    const bf16* __restrict__ Bt, const float* __restrict__ bias,
    const TRES* __restrict__ res, TOUT* __restrict__ Cv,
    float* __restrict__ out2, int M, int N, int K)
{
  __shared__ alignas(16) bf16 As[2][128 * 32];
  __shared__ alignas(16) bf16 Bs[2][128 * 32];
  const int tid = threadIdx.x;
  const int m0 = blockIdx.y * 128;
  const int n0 = blockIdx.x * 128;
  const int lane = tid & 63;
  const int wave = tid >> 6;
  const int wm = (wave >> 1) * 64;
  const int wn = (wave & 1) * 64;
  const int fr = lane & 15;
  const int fq = lane >> 4;
  const int srow = wave * 32 + (lane >> 2);   // staged row for this lane
  const int scol = (lane & 3) * 8;            // bf16 col offset (16B granule)
  const int lofs = wave * 32 * 32;            // wave's LDS chunk within a buffer

  const bf16* gaBase = A  + (size_t)(m0 + srow) * K + scol;
  const bf16* gbBase = Bt + (size_t)(n0 + srow) * K + scol;

  f32x4 acc[4][4];
  #pragma unroll
  for (int i = 0; i < 4; i++)
    #pragma unroll
    for (int j = 0; j < 4; j++) acc[i][j] = (f32x4){0.f, 0.f, 0.f, 0.f};

  auto stage = [&](int buf, int kt) {
    const bf16* ga = gaBase + kt;
    const bf16* gb = gbBase + kt;
    bf16* la = &As[buf][lofs];
    bf16* lb = &Bs[buf][lofs];
    gl_lds16(ga, la);            gl_lds16(ga + (size_t)16 * K, la + 16 * 32);
    gl_lds16(gb, lb);            gl_lds16(gb + (size_t)16 * K, lb + 16 * 32);
  };

  stage(0, 0);
  int cur = 0;
  for (int kt = 0; kt < K; kt += 32) {
    __syncthreads();                       // drains stage(cur); frees buf cur^1
    if (kt + 32 < K) stage(cur ^ 1, kt + 32);   // async prefetch next tile
    short8 af[4], bfv[4];
    #pragma unroll
    for (int mi = 0; mi < 4; mi++)
      af[mi] = *reinterpret_cast<const short8*>(&As[cur][(wm + mi * 16 + fr) * 32 + fq * 8]);
    #pragma unroll
    for (int ni = 0; ni < 4; ni++)
      bfv[ni] = *reinterpret_cast<const short8*>(&Bs[cur][(wn + ni * 16 + fr) * 32 + fq * 8]);
    #pragma unroll
    for (int mi = 0; mi < 4; mi++)
      #pragma unroll
      for (int ni = 0; ni < 4; ni++)
        acc[mi][ni] = __builtin_amdgcn_mfma_f32_16x16x32_bf16(af[mi], bfv[ni],
                                                              acc[mi][ni], 0, 0, 0);
    cur ^= 1;
  }

  // epilogue: C/D layout col = lane&15, row = (lane>>4)*4 + reg
  #pragma unroll
  for (int ni = 0; ni < 4; ni++) {
    int n = n0 + wn + ni * 16 + fr;
    float bv = bias[n];
    #pragma unroll
    for (int mi = 0; mi < 4; mi++) {
      int mbase = m0 + wm + mi * 16 + fq * 4;
      if (EPI == 3) {
        int b = mbase >> 12, l = mbase & 4095;
        size_t o = ((size_t)(b * 512 + n) << 12) + l;
        float4 xr = *reinterpret_cast<const float4*>(&((const float*)res)[o]);
        float4 vv;
        vv.x = acc[mi][ni][0] + bv + xr.x;
        vv.y = acc[mi][ni][1] + bv + xr.y;
        vv.z = acc[mi][ni][2] + bv + xr.z;
        vv.w = acc[mi][ni][3] + bv + xr.w;
        *reinterpret_cast<float4*>(&((float*)Cv)[o]) = vv;
      } else if (EPI == 4) {
        #pragma unroll
        for (int r = 0; r < 4; r++) {
          float v = acc[mi][ni][r] + bv;
          if (n0 < 512) ((bf16*)Cv)[(size_t)(mbase + r) * 512 + n] = f2b(v);
          else          out2[(size_t)(mbase + r) * 256 + (n - 512)] = v;
        }
      } else {
        #pragma unroll
        for (int r = 0; r < 4; r++) {
          size_t idx = (size_t)(mbase + r) * N + n;
          float v = acc[mi][ni][r] + bv;
          if (EPI == 1) {
            float rv;
            if constexpr (sizeof(TRES) == 2) rv = b2f(((const bf16*)res)[idx]);
            else                             rv = ((const float*)res)[idx];
            v += rv;
          }
          if constexpr (sizeof(TOUT) == 2) ((bf16*)Cv)[idx] = f2b(v);
          else                             ((float*)Cv)[idx] = v;
        }
      }
    }
  }
}

// ------- interleaved GEGLU GEMM: Wt rows 2c = Wa[:,c], 2c+1 = Wg[:,c] ------
// Single accumulator set (64 AGPRs). ffin[m][c] = (a+ba)*gelu(g+bg),
// a in even fr lanes, g in odd fr lanes -> exchange via shfl_xor(1).
__global__ __launch_bounds__(256) void gemm_geglu2(const bf16* __restrict__ A,
    const bf16* __restrict__ Wt, const float* __restrict__ gb,
    bf16* __restrict__ Cv, int K)
{
  __shared__ alignas(16) bf16 As[2][128 * 32];
  __shared__ alignas(16) bf16 Bs[2][128 * 32];
  const int tid = threadIdx.x;
  const int m0 = blockIdx.y * 128;
  const int n0 = blockIdx.x * 128;       // interleaved-row space (0..4095)
  const int lane = tid & 63;
  const int wave = tid >> 6;
  const int wm = (wave >> 1) * 64;
  const int wn = (wave & 1) * 64;
  const int fr = lane & 15;
  const int fq = lane >> 4;
  const int srow = wave * 32 + (lane >> 2);
  const int scol = (lane & 3) * 8;
  const int lofs = wave * 32 * 32;

  const bf16* gaBase = A  + (size_t)(m0 + srow) * K + scol;
  const bf16* gbBase = Wt + (size_t)(n0 + srow) * K + scol;

  f32x4 acc[4][4];
  #pragma unroll
  for (int i = 0; i < 4; i++)
    #pragma unroll
    for (int j = 0; j < 4; j++) acc[i][j] = (f32x4){0.f, 0.f, 0.f, 0.f};

  auto stage = [&](int buf, int kt) {
    const bf16* ga = gaBase + kt;
    const bf16* gb2 = gbBase + kt;
    bf16* la = &As[buf][lofs];
    bf16* lb = &Bs[buf][lofs];
    gl_lds16(ga, la);             gl_lds16(ga + (size_t)16 * K, la + 16 * 32);
    gl_lds16(gb2, lb);            gl_lds16(gb2 + (size_t)16 * K, lb + 16 * 32);
  };

  stage(0, 0);
  int cur = 0;
  for (int kt = 0; kt < K; kt += 32) {
    __syncthreads();
    if (kt + 32 < K) stage(cur ^ 1, kt + 32);
    short8 af[4], bfv[4];
    #pragma unroll
    for (int mi = 0; mi < 4; mi++)
      af[mi] = *reinterpret_cast<const short8*>(&As[cur][(wm + mi * 16 + fr) * 32 + fq * 8]);
    #pragma unroll
    for (int ni = 0; ni < 4; ni++)
      bfv[ni] = *reinterpret_cast<const short8*>(&Bs[cur][(wn + ni * 16 + fr) * 32 + fq * 8]);
    #pragma unroll
    for (int mi = 0; mi < 4; mi++)
      #pragma unroll
      for (int ni = 0; ni < 4; ni++)
        acc[mi][ni] = __builtin_amdgcn_mfma_f32_16x16x32_bf16(af[mi], bfv[ni],
                                                              acc[mi][ni], 0, 0, 0);
    cur ^= 1;
  }

  const bool isA = (fr & 1) == 0;
  #pragma unroll
  for (int ni = 0; ni < 4; ni++) {
    int nint = n0 + wn + ni * 16 + fr;         // interleaved row id
    int col = nint >> 1;                       // output column (even lanes exact)
    float ba = gb[col];
    float bg = gb[2048 + col];
    #pragma unroll
    for (int mi = 0; mi < 4; mi++) {
      int mbase = m0 + wm + mi * 16 + fq * 4;
      #pragma unroll
      for (int r = 0; r < 4; r++) {
        float val = acc[mi][ni][r];
        float partner = __shfl_xor(val, 1, 64);  // odd lane's g (for even lanes)
        if (isA) {
          float a = val + ba;
          float g = partner + bg;
          Cv[(size_t)(mbase + r) * 2048 + col] = f2b(a * fast_gelu(g));
        }
      }
    }
  }
}

// ---------------- MSDA: degenerate deformable attention (Hl=L, Wl=1) ------
// sa: [M][256] fp32: cols 0..127 = sampling offsets, 128..191 = attn logits
__global__ __launch_bounds__(256) void msda_k(const float* __restrict__ sa,
    const bf16* __restrict__ v2, bf16* __restrict__ outp)
{
  int unit = blockIdx.x * 4 + (threadIdx.x >> 6);  // (b*L+l)*8 + h
  int lane = threadIdx.x & 63;
  int m = unit >> 3;
  int h = unit & 7;
  int b = m >> 12;                                  // L = 4096
  const float* lg = &sa[(size_t)m * 256 + 128 + h * 8];
  float w[8], mx = -1e30f;
  #pragma unroll
  for (int p = 0; p < 8; p++) { w[p] = lg[p]; mx = fmaxf(mx, w[p]); }
  float sum = 0.f;
  #pragma unroll
  for (int p = 0; p < 8; p++) { w[p] = expf(w[p] - mx); sum += w[p]; }
  float rs = 1.f / sum;
  const float* op = &sa[(size_t)m * 256 + h * 16];
  size_t vbase = ((size_t)b * 4096) * 512 + h * 64 + lane;
  float acc = 0.f;
  #pragma unroll
  for (int p = 0; p < 8; p++) {
    float ox = op[p * 2 + 0], oy = op[p * 2 + 1];
    float gx = 2.f * (0.5f + ox) - 1.f;
    float px = ((gx + 1.f) * 1.f - 1.f) * 0.5f;              // = ox (mirrors ref fp ops)
    float gy = 2.f * (0.5f + oy * (1.f / 4096.f)) - 1.f;
    float py = ((gy + 1.f) * 4096.f - 1.f) * 0.5f;           // = oy + 2047.5
    float x0 = floorf(px), y0 = floorf(py);
    float lx = px - x0, ly = py - y0;
    int xi = (int)x0;
    int yi = (int)y0;
    float wx = (xi == 0) ? (1.f - lx) : ((xi == -1) ? lx : 0.f);
    if (wx != 0.f) {                         // wave-uniform branch
      float s = 0.f;
      if (yi >= 0 && yi < 4096)  s += (1.f - ly) * b2f(v2[vbase + (size_t)yi * 512]);
      if (yi >= -1 && yi < 4095) s += ly * b2f(v2[vbase + (size_t)(yi + 1) * 512]);
      acc += w[p] * rs * wx * s;
    }
  }
  outp[(size_t)m * 512 + h * 64 + lane] = f2b(acc);
}

// =========================================================================
extern "C" void kernel_launch(void* const* d_in, const int* in_sizes, int n_in,
                              void* d_out, int out_size, void* d_ws, size_t ws_size,
                              hipStream_t stream)
{
  if (n_in < 27) return;
  const float* x       = (const float*)d_in[0];
  const float* gn_g    = (const float*)d_in[1];
  const float* gn_b    = (const float*)d_in[2];
  const float* pin_w   = (const float*)d_in[3];
  const float* pin_b   = (const float*)d_in[4];
  const float* ln1_g   = (const float*)d_in[5];
  const float* ln1_b   = (const float*)d_in[6];
  const float* vproj_w = (const float*)d_in[7];
  const float* vproj_b = (const float*)d_in[8];
  const float* mvp_w   = (const float*)d_in[9];
  const float* mvp_b   = (const float*)d_in[10];
  const float* soff_w  = (const float*)d_in[11];
  const float* soff_b  = (const float*)d_in[12];
  const float* attw_w  = (const float*)d_in[13];
  const float* attw_b  = (const float*)d_in[14];
  const float* mop_w   = (const float*)d_in[15];
  const float* mop_b   = (const float*)d_in[16];
  const float* dout_w  = (const float*)d_in[17];
  const float* dout_b  = (const float*)d_in[18];
  const float* ln3_g   = (const float*)d_in[19];
  const float* ln3_b   = (const float*)d_in[20];
  const float* geglu_w = (const float*)d_in[21];
  const float* geglu_b = (const float*)d_in[22];
  const float* dense_w = (const float*)d_in[23];
  const float* dense_b = (const float*)d_in[24];
  const float* pout_w  = (const float*)d_in[25];
  const float* pout_b  = (const float*)d_in[26];
  float* out = (float*)d_out;

  char* ws = (char*)d_ws;
  size_t off = 0;
  auto alloc = [&](size_t bytes) -> char* {
    off = (off + 255) & ~(size_t)255;
    char* p = ws + off;
    off += bytes;
    return p;
  };
  // persistent weights (bf16, transposed)
  bf16* wtPin   = (bf16*)alloc(512 * 512 * 2);
  bf16* wtBig   = (bf16*)alloc(768 * 512 * 2);     // [vproj 512 | soff 128 | attw 64 | pad 64]
  bf16* wtMvp   = (bf16*)alloc(512 * 512 * 2);
  bf16* wtMop   = (bf16*)alloc(512 * 512 * 2);
  bf16* wtDout  = (bf16*)alloc(512 * 512 * 2);
  bf16* wtPout  = (bf16*)alloc(512 * 512 * 2);
  bf16* wtGeglu = (bf16*)alloc((size_t)4096 * 512 * 2);   // interleaved a/g rows
  bf16* wtDense = (bf16*)alloc((size_t)512 * 2048 * 2);
  float* biasBig = (float*)alloc(768 * 4);
  float* stats   = (float*)alloc(64 * 4);
  // activation regions with liveness-checked unions
  char* A  = alloc(32 * MB);  // t32 (early) | hn@0 (16MB) + t3@16MB
  char* Cg = alloc(32 * MB);  // t2 (fp32)
  char* D  = alloc(64 * MB);  // xnt@0, v@16, v2@32, msda@48
  char* E  = alloc(64 * MB);  // q16@0, sa32@16 (16MB), m2@32 (16MB) | ffin@0 (64MB)
  if (off > ws_size) return;  // workspace too small — fail loudly (zero output)

  float* t32   = (float*)A;
  bf16*  hn    = (bf16*)A;
  bf16*  t3    = (bf16*)(A + 16 * MB);
  float* t2    = (float*)Cg;
  bf16*  xnt   = (bf16*)D;
  bf16*  v16   = (bf16*)(D + 16 * MB);
  bf16*  v2b   = (bf16*)(D + 32 * MB);
  bf16*  msda  = (bf16*)(D + 48 * MB);
  bf16*  q16   = (bf16*)E;
  float* sa32  = (float*)(E + 16 * MB);
  bf16*  m2    = (bf16*)(E + 32 * MB);
  bf16*  ffin  = (bf16*)E;

  hipMemsetAsync(stats, 0, 64 * 4, stream);
  pack_bias_big<<<3, 256, 0, stream>>>(vproj_b, soff_b, attw_b, biasBig);

  // fused transpose: 11 jobs
  TransJobs J{};
  auto setJob = [&](int j, const float* src, bf16* dst, int K, int N, int Npad,
                    int ss, int sc, int a, int b) {
    J.src[j] = src; J.dst[j] = dst; J.K[j] = K; J.N[j] = N;
    J.srcStride[j] = ss; J.srcColOff[j] = sc; J.a[j] = a; J.b[j] = b;
    J.tileStart[j + 1] = J.tileStart[j] + (K / 32) * (Npad / 32);
  };
  J.tileStart[0] = 0;
  setJob(0,  pin_w,   wtPin,   512, 512,  512,  512,  0,    1, 0);
  setJob(1,  vproj_w, wtBig,   512, 512,  512,  512,  0,    1, 0);
  setJob(2,  soff_w,  wtBig,   512, 128,  128,  128,  0,    1, 512);
  setJob(3,  attw_w,  wtBig,   512, 64,   128,  64,   0,    1, 640);
  setJob(4,  mvp_w,   wtMvp,   512, 512,  512,  512,  0,    1, 0);
  setJob(5,  mop_w,   wtMop,   512, 512,  512,  512,  0,    1, 0);
  setJob(6,  dout_w,  wtDout,  512, 512,  512,  512,  0,    1, 0);
  setJob(7,  pout_w,  wtPout,  512, 512,  512,  512,  0,    1, 0);
  setJob(8,  geglu_w, wtGeglu, 512, 2048, 2048, 4096, 0,    2, 0);  // a-half -> rows 2c
  setJob(9,  geglu_w, wtGeglu, 512, 2048, 2048, 4096, 2048, 2, 1);  // g-half -> rows 2c+1
  setJob(10, dense_w, wtDense, 2048, 512, 512,  512,  0,    1, 0);
  transpose_all<<<J.tileStart[11], dim3(32, 8), 0, stream>>>(J);

  dim3 tb(32, 8);
  gn_partial<<<512, 256, 0, stream>>>(x, stats);
  gn_apply_t<<<dim3(128, 16, 4), tb, 0, stream>>>(x, stats, gn_g, gn_b, xnt);

  // t = xnt @ pin + b   (fp32 trunk)
  gemm_bt<float, float, 0><<<dim3(4, 128), 256, 0, stream>>>(
      xnt, wtPin, pin_b, nullptr, t32, nullptr, M_, 512, 512);
  // q = LN1(t)
  layernorm_k<<<4096, 256, 0, stream>>>(t32, ln1_g, ln1_b, q16);
  // fused: value = q @ vproj (bf16) ; sa = q @ [soff|attw] (fp32)
  gemm_bt<bf16, float, 4><<<dim3(6, 128), 256, 0, stream>>>(
      q16, wtBig, biasBig, nullptr, v16, sa32, M_, 768, 512);
  // v2 = value @ mvp
  gemm_bt<bf16, float, 0><<<dim3(4, 128), 256, 0, stream>>>(
      v16, wtMvp, mvp_b, nullptr, v2b, nullptr, M_, 512, 512);
  msda_k<<<32768, 256, 0, stream>>>(sa32, v2b, msda);
  // m2 = msda @ mop + b + q ; t2 = m2 @ dout + b + t (fp32 trunk)
  gemm_bt<bf16, bf16, 1><<<dim3(4, 128), 256, 0, stream>>>(
      msda, wtMop, mop_b, q16, m2, nullptr, M_, 512, 512);
  gemm_bt<float, float, 1><<<dim3(4, 128), 256, 0, stream>>>(
      m2, wtDout, dout_b, t32, t2, nullptr, M_, 512, 512);
  // hn = LN3(t2)
  layernorm_k<<<4096, 256, 0, stream>>>(t2, ln3_g, ln3_b, hn);
  // ffin = (hn @ Wa + ba) * gelu(hn @ Wg + bg)   — interleaved GEGLU, N=4096
  gemm_geglu2<<<dim3(32, 128), 256, 0, stream>>>(hn, wtGeglu, geglu_b, ffin, 512);
  // t3 = ffin @ dense + b + t2
  gemm_bt<bf16, float, 1><<<dim3(4, 128), 256, 0, stream>>>(
      ffin, wtDense, dense_b, t2, t3, nullptr, M_, 512, 2048);
  // out[b,c,l] = (t3 @ pout + b)[b,l,c] + x[b,c,l]   (fused transpose epilogue)
  gemm_bt<float, float, 3><<<dim3(4, 128), 256, 0, stream>>>(
      t3, wtPout, pout_b, x, out, nullptr, M_, 512, 512);
}

// Round 6
// 562.619 us; speedup vs baseline: 1.1780x; 1.0631x over previous
//
#include <hip/hip_runtime.h>
#include <hip/hip_bf16.h>
#include <math.h>

using bf16 = __hip_bfloat16;
typedef __attribute__((ext_vector_type(8))) short short8;
typedef __attribute__((ext_vector_type(4))) float f32x4;

static constexpr int B_ = 4, C_ = 512, L_ = 4096, M_ = 16384;
static constexpr size_t MB = 1ull << 20;

__device__ __forceinline__ float b2f(bf16 v){ return __bfloat162float(v); }
__device__ __forceinline__ bf16  f2b(float v){ return __float2bfloat16(v); }

// async global -> LDS, 16B per lane, lane l lands at (wave-uniform base) + l*16
__device__ __forceinline__ void gl_lds16(const bf16* g, bf16* l) {
  __builtin_amdgcn_global_load_lds(
      (const __attribute__((address_space(1))) unsigned int*)g,
      (__attribute__((address_space(3))) unsigned int*)l, 16, 0, 0);
}

// gelu(g) = 0.5 g (1 + erf(g/sqrt2)); erf via A&S 7.1.26 (|eps| < 1.5e-7)
__device__ __forceinline__ float fast_gelu(float g) {
  float t  = g * 0.70710678118654752f;
  float at = fabsf(t);
  float k  = 1.f / (1.f + 0.3275911f * at);
  float poly = k * (0.254829592f + k * (-0.284496736f + k * (1.421413741f +
               k * (-1.453152027f + k * 1.061405429f))));
  float erfv = 1.f - poly * __expf(-at * at);
  erfv = __builtin_copysignf(erfv, t);
  return 0.5f * g * (1.f + erfv);
}

// ---------------- fused weight transpose: 11 jobs in one dispatch ----------
// mode a==1: dst row = n + b.  mode a==2: granule-16 geglu interleave:
//   dst row = ((n>>4)<<5) + b*16 + (n&15)   (b=0: a-half, b=1: gate-half)
struct TransJobs {
  const float* src[11];
  bf16* dst[11];
  int K[11], N[11], srcStride[11], srcColOff[11], a[11], b[11];
  int tileStart[12];
};

__global__ __launch_bounds__(256) void transpose_all(TransJobs J)
{
  __shared__ float tile[32][33];
  int t = blockIdx.x;
  int j = 0;
  #pragma unroll
  for (int q = 0; q < 10; q++) if (t >= J.tileStart[q + 1]) j = q + 1;
  t -= J.tileStart[j];
  const int kTiles = J.K[j] >> 5;
  const int k0 = (t % kTiles) * 32, n0 = (t / kTiles) * 32;
  const int tx = threadIdx.x, ty = threadIdx.y;
  const float* src = J.src[j];
  const int N = J.N[j], ss = J.srcStride[j], sc = J.srcColOff[j];
  #pragma unroll
  for (int i = 0; i < 32; i += 8) {
    int k = k0 + ty + i, n = n0 + tx;
    tile[ty + i][tx] = (n < N) ? src[(size_t)k * ss + sc + n] : 0.f;
  }
  __syncthreads();
  bf16* dst = J.dst[j];
  const int a = J.a[j], b = J.b[j], K = J.K[j];
  #pragma unroll
  for (int i = 0; i < 32; i += 8) {
    int n = n0 + ty + i, k = k0 + tx;
    int row = (a == 2) ? (((n >> 4) << 5) + b * 16 + (n & 15)) : (n + b);
    dst[(size_t)row * K + k] = f2b(tile[tx][ty + i]);
  }
}

// combined bias [vproj(512) | soff(128) | attw(64) | zero(64)]
__global__ void pack_bias_big(const float* __restrict__ vb,
    const float* __restrict__ sb, const float* __restrict__ ab,
    float* __restrict__ bp){
  int i = blockIdx.x * 256 + threadIdx.x;   // 768 threads
  float v = 0.f;
  if (i < 512) v = vb[i];
  else if (i < 640) v = sb[i - 512];
  else if (i < 704) v = ab[i - 640];
  bp[i] = v;
}

// ---------------- GroupNorm stats (sum, sumsq per (b,g)) ----------------
__global__ __launch_bounds__(256) void gn_partial(const float* __restrict__ x,
                                                  float* __restrict__ stats)
{
  int bg = blockIdx.x >> 4;
  int sc = blockIdx.x & 15;
  size_t base = (size_t)bg * 262144 + (size_t)sc * 16384;
  int tid = threadIdx.x;
  float s = 0.f, s2 = 0.f;
  #pragma unroll
  for (int i = 0; i < 8; i++) {
    size_t o = base + ((size_t)i * 256 + tid) * 8;
    float4 a = *reinterpret_cast<const float4*>(&x[o]);
    float4 b = *reinterpret_cast<const float4*>(&x[o + 4]);
    s  += a.x + a.y + a.z + a.w + b.x + b.y + b.z + b.w;
    s2 += a.x*a.x + a.y*a.y + a.z*a.z + a.w*a.w
        + b.x*b.x + b.y*b.y + b.z*b.z + b.w*b.w;
  }
  #pragma unroll
  for (int o = 32; o; o >>= 1) { s += __shfl_xor(s, o, 64); s2 += __shfl_xor(s2, o, 64); }
  __shared__ float ls[4], ls2[4];
  int wave = tid >> 6, lane = tid & 63;
  if (lane == 0) { ls[wave] = s; ls2[wave] = s2; }
  __syncthreads();
  if (tid == 0) {
    atomicAdd(&stats[bg * 2 + 0], ls[0] + ls[1] + ls[2] + ls[3]);
    atomicAdd(&stats[bg * 2 + 1], ls2[0] + ls2[1] + ls2[2] + ls2[3]);
  }
}

// ---------------- GN apply + transpose (B,C,L) -> (B*L, C) bf16 ----------
__global__ __launch_bounds__(256) void gn_apply_t(const float* __restrict__ x,
    const float* __restrict__ stats, const float* __restrict__ gg,
    const float* __restrict__ gb, bf16* __restrict__ xnt)
{
  __shared__ float tile[32][33];
  int b = blockIdx.z, c0 = blockIdx.y * 32, l0 = blockIdx.x * 32;
  int tx = threadIdx.x, ty = threadIdx.y;
  #pragma unroll
  for (int i = 0; i < 32; i += 8) {
    int c = c0 + ty + i, l = l0 + tx;
    int grp = b * 8 + (c >> 6);
    float sum = stats[grp * 2], ss = stats[grp * 2 + 1];
    float mu = sum * (1.f / 262144.f);
    float inv = rsqrtf(ss * (1.f / 262144.f) - mu * mu + 1e-5f);
    float v = x[((size_t)b * 512 + c) * 4096 + l];
    tile[ty + i][tx] = (v - mu) * inv * gg[c] + gb[c];
  }
  __syncthreads();
  #pragma unroll
  for (int i = 0; i < 32; i += 8) {
    int l = l0 + ty + i, c = c0 + tx;
    xnt[((size_t)b * 4096 + l) * 512 + c] = f2b(tile[tx][ty + i]);
  }
}

// ---------------- LayerNorm over C=512: fp32 in, bf16 out, 1 wave/row -----
__global__ __launch_bounds__(256) void layernorm_k(const float* __restrict__ X,
    const float* __restrict__ g, const float* __restrict__ b, bf16* __restrict__ Y)
{
  int row = blockIdx.x * 4 + (threadIdx.x >> 6);
  int lane = threadIdx.x & 63;
  const float* xr = X + (size_t)row * 512 + lane * 8;
  float4 a = *reinterpret_cast<const float4*>(xr);
  float4 c = *reinterpret_cast<const float4*>(xr + 4);
  float v[8] = {a.x, a.y, a.z, a.w, c.x, c.y, c.z, c.w};
  float s = 0.f, s2 = 0.f;
  #pragma unroll
  for (int i = 0; i < 8; i++) { s += v[i]; s2 += v[i] * v[i]; }
  #pragma unroll
  for (int o = 32; o; o >>= 1) { s += __shfl_xor(s, o, 64); s2 += __shfl_xor(s2, o, 64); }
  float mu = s * (1.f / 512.f);
  float inv = rsqrtf(s2 * (1.f / 512.f) - mu * mu + 1e-5f);
  float4 g0 = *reinterpret_cast<const float4*>(&g[lane * 8]);
  float4 g1 = *reinterpret_cast<const float4*>(&g[lane * 8 + 4]);
  float4 b0 = *reinterpret_cast<const float4*>(&b[lane * 8]);
  float4 b1 = *reinterpret_cast<const float4*>(&b[lane * 8 + 4]);
  float gv[8] = {g0.x, g0.y, g0.z, g0.w, g1.x, g1.y, g1.z, g1.w};
  float bv[8] = {b0.x, b0.y, b0.z, b0.w, b1.x, b1.y, b1.z, b1.w};
  bf16 outv[8];
  #pragma unroll
  for (int i = 0; i < 8; i++) outv[i] = f2b((v[i] - mu) * inv * gv[i] + bv[i]);
  *reinterpret_cast<uint4*>(Y + (size_t)row * 512 + lane * 8) =
      *reinterpret_cast<const uint4*>(outv);
}

// ------- MFMA GEMM, 64x128 tile, dbuf async staging, 4-5 blocks/CU --------
// C[M,N] = A[M,K] * Bt[N,K]^T + bias (+epi). Wave w: wm=(w>>1)*32, wn=(w&1)*64,
// frags 2(m) x 4(n), acc = 32 AGPRs.
// EPI: 0 none | 1 += res[idx] | 3 transpose+residual fp32 out
// EPI 4: n0<512 -> bf16 Cv[m*512+n]; n0>=512 -> fp32 out2[m*256+n-512]
template<typename TOUT, typename TRES, int EPI>
__global__ __launch_bounds__(256) void gemm_bt(const bf16* __restrict__ A,
    const bf16* __restrict__ Bt, const float* __restrict__ bias,
    const TRES* __restrict__ res, TOUT* __restrict__ Cv,
    float* __restrict__ out2, int M, int N, int K)
{
  __shared__ alignas(16) bf16 As[2][64 * 32];
  __shared__ alignas(16) bf16 Bs[2][128 * 32];
  const int tid = threadIdx.x;
  const int m0 = blockIdx.y * 64;
  const int n0 = blockIdx.x * 128;
  const int lane = tid & 63;
  const int wave = tid >> 6;
  const int wm = (wave >> 1) * 32;
  const int wn = (wave & 1) * 64;
  const int fr = lane & 15;
  const int fq = lane >> 4;
  const int srow = wave * 16 + (lane >> 2);   // staged row (per call)
  const int scol = (lane & 3) * 8;            // bf16 col offset (16B granule)
  const int lofs = wave * 16 * 32;            // wave-uniform LDS chunk base

  const bf16* gaBase = A  + (size_t)(m0 + srow) * K + scol;
  const bf16* gbBase = Bt + (size_t)(n0 + srow) * K + scol;

  f32x4 acc[2][4];
  #pragma unroll
  for (int i = 0; i < 2; i++)
    #pragma unroll
    for (int j = 0; j < 4; j++) acc[i][j] = (f32x4){0.f, 0.f, 0.f, 0.f};

  auto stage = [&](int buf, int kt) {
    gl_lds16(gaBase + kt, &As[buf][lofs]);
    gl_lds16(gbBase + kt, &Bs[buf][lofs]);
    gl_lds16(gbBase + (size_t)64 * K + kt, &Bs[buf][64 * 32 + lofs]);
  };

  stage(0, 0);
  int cur = 0;
  for (int kt = 0; kt < K; kt += 32) {
    __syncthreads();                            // drains stage(cur)
    if (kt + 32 < K) stage(cur ^ 1, kt + 32);   // async prefetch next tile
    short8 af[2], bfv[4];
    #pragma unroll
    for (int mi = 0; mi < 2; mi++)
      af[mi] = *reinterpret_cast<const short8*>(&As[cur][(wm + mi * 16 + fr) * 32 + fq * 8]);
    #pragma unroll
    for (int ni = 0; ni < 4; ni++)
      bfv[ni] = *reinterpret_cast<const short8*>(&Bs[cur][(wn + ni * 16 + fr) * 32 + fq * 8]);
    #pragma unroll
    for (int mi = 0; mi < 2; mi++)
      #pragma unroll
      for (int ni = 0; ni < 4; ni++)
        acc[mi][ni] = __builtin_amdgcn_mfma_f32_16x16x32_bf16(af[mi], bfv[ni],
                                                              acc[mi][ni], 0, 0, 0);
    cur ^= 1;
  }

  // epilogue: C/D layout col = lane&15, row = (lane>>4)*4 + reg
  #pragma unroll
  for (int ni = 0; ni < 4; ni++) {
    int n = n0 + wn + ni * 16 + fr;
    float bv = bias[n];
    #pragma unroll
    for (int mi = 0; mi < 2; mi++) {
      int mbase = m0 + wm + mi * 16 + fq * 4;
      if (EPI == 3) {
        int b = mbase >> 12, l = mbase & 4095;
        size_t o = ((size_t)(b * 512 + n) << 12) + l;
        float4 xr = *reinterpret_cast<const float4*>(&((const float*)res)[o]);
        float4 vv;
        vv.x = acc[mi][ni][0] + bv + xr.x;
        vv.y = acc[mi][ni][1] + bv + xr.y;
        vv.z = acc[mi][ni][2] + bv + xr.z;
        vv.w = acc[mi][ni][3] + bv + xr.w;
        *reinterpret_cast<float4*>(&((float*)Cv)[o]) = vv;
      } else if (EPI == 4) {
        #pragma unroll
        for (int r = 0; r < 4; r++) {
          float v = acc[mi][ni][r] + bv;
          if (n0 < 512) ((bf16*)Cv)[(size_t)(mbase + r) * 512 + n] = f2b(v);
          else          out2[(size_t)(mbase + r) * 256 + (n - 512)] = v;
        }
      } else {
        #pragma unroll
        for (int r = 0; r < 4; r++) {
          size_t idx = (size_t)(mbase + r) * N + n;
          float v = acc[mi][ni][r] + bv;
          if (EPI == 1) {
            float rv;
            if constexpr (sizeof(TRES) == 2) rv = b2f(((const bf16*)res)[idx]);
            else                             rv = ((const float*)res)[idx];
            v += rv;
          }
          if constexpr (sizeof(TOUT) == 2) ((bf16*)Cv)[idx] = f2b(v);
          else                             ((float*)Cv)[idx] = v;
        }
      }
    }
  }
}

// --- GEGLU GEMM, granule-16 interleave: rows 32j..32j+15 = Wa cols 16j..16j+15,
//     rows 32j+16..32j+31 = Wg same cols. a and g land in the SAME lane:
//     acc[mi][2p] = a, acc[mi][2p+1] = g for col = ((n0+wn)>>1) + p*16 + fr.
__global__ __launch_bounds__(256) void gemm_geglu2(const bf16* __restrict__ A,
    const bf16* __restrict__ Wt, const float* __restrict__ gb,
    bf16* __restrict__ Cv, int K)
{
  __shared__ alignas(16) bf16 As[2][64 * 32];
  __shared__ alignas(16) bf16 Bs[2][128 * 32];
  const int tid = threadIdx.x;
  const int m0 = blockIdx.y * 64;
  const int n0 = blockIdx.x * 128;       // interleaved-row space (0..4095)
  const int lane = tid & 63;
  const int wave = tid >> 6;
  const int wm = (wave >> 1) * 32;
  const int wn = (wave & 1) * 64;
  const int fr = lane & 15;
  const int fq = lane >> 4;
  const int srow = wave * 16 + (lane >> 2);
  const int scol = (lane & 3) * 8;
  const int lofs = wave * 16 * 32;

  const bf16* gaBase = A  + (size_t)(m0 + srow) * K + scol;
  const bf16* gbBase = Wt + (size_t)(n0 + srow) * K + scol;

  f32x4 acc[2][4];
  #pragma unroll
  for (int i = 0; i < 2; i++)
    #pragma unroll
    for (int j = 0; j < 4; j++) acc[i][j] = (f32x4){0.f, 0.f, 0.f, 0.f};

  auto stage = [&](int buf, int kt) {
    gl_lds16(gaBase + kt, &As[buf][lofs]);
    gl_lds16(gbBase + kt, &Bs[buf][lofs]);
    gl_lds16(gbBase + (size_t)64 * K + kt, &Bs[buf][64 * 32 + lofs]);
  };

  stage(0, 0);
  int cur = 0;
  for (int kt = 0; kt < K; kt += 32) {
    __syncthreads();
    if (kt + 32 < K) stage(cur ^ 1, kt + 32);
    short8 af[2], bfv[4];
    #pragma unroll
    for (int mi = 0; mi < 2; mi++)
      af[mi] = *reinterpret_cast<const short8*>(&As[cur][(wm + mi * 16 + fr) * 32 + fq * 8]);
    #pragma unroll
    for (int ni = 0; ni < 4; ni++)
      bfv[ni] = *reinterpret_cast<const short8*>(&Bs[cur][(wn + ni * 16 + fr) * 32 + fq * 8]);
    #pragma unroll
    for (int mi = 0; mi < 2; mi++)
      #pragma unroll
      for (int ni = 0; ni < 4; ni++)
        acc[mi][ni] = __builtin_amdgcn_mfma_f32_16x16x32_bf16(af[mi], bfv[ni],
                                                              acc[mi][ni], 0, 0, 0);
    cur ^= 1;
  }

  const int cbase = (n0 + wn) >> 1;
  #pragma unroll
  for (int pi = 0; pi < 2; pi++) {
    int col = cbase + pi * 16 + fr;
    float ba = gb[col];
    float bg = gb[2048 + col];
    #pragma unroll
    for (int mi = 0; mi < 2; mi++) {
      int mbase = m0 + wm + mi * 16 + fq * 4;
      #pragma unroll
      for (int r = 0; r < 4; r++) {
        float a = acc[mi][2 * pi][r] + ba;
        float g = acc[mi][2 * pi + 1][r] + bg;
        Cv[(size_t)(mbase + r) * 2048 + col] = f2b(a * fast_gelu(g));
      }
    }
  }
}

// ---------------- MSDA: degenerate deformable attention (Hl=L, Wl=1) ------
// sa: [M][256] fp32: cols 0..127 = sampling offsets, 128..191 = attn logits
__global__ __launch_bounds__(256) void msda_k(const float* __restrict__ sa,
    const bf16* __restrict__ v2, bf16* __restrict__ outp)
{
  int unit = blockIdx.x * 4 + (threadIdx.x >> 6);  // (b*L+l)*8 + h
  int lane = threadIdx.x & 63;
  int m = unit >> 3;
  int h = unit & 7;
  int b = m >> 12;                                  // L = 4096
  const float* lg = &sa[(size_t)m * 256 + 128 + h * 8];
  float w[8], mx = -1e30f;
  #pragma unroll
  for (int p = 0; p < 8; p++) { w[p] = lg[p]; mx = fmaxf(mx, w[p]); }
  float sum = 0.f;
  #pragma unroll
  for (int p = 0; p < 8; p++) { w[p] = expf(w[p] - mx); sum += w[p]; }
  float rs = 1.f / sum;
  const float* op = &sa[(size_t)m * 256 + h * 16];
  size_t vbase = ((size_t)b * 4096) * 512 + h * 64 + lane;
  float acc = 0.f;
  #pragma unroll
  for (int p = 0; p < 8; p++) {
    float ox = op[p * 2 + 0], oy = op[p * 2 + 1];
    float gx = 2.f * (0.5f + ox) - 1.f;
    float px = ((gx + 1.f) * 1.f - 1.f) * 0.5f;              // = ox (mirrors ref fp ops)
    float gy = 2.f * (0.5f + oy * (1.f / 4096.f)) - 1.f;
    float py = ((gy + 1.f) * 4096.f - 1.f) * 0.5f;           // = oy + 2047.5
    float x0 = floorf(px), y0 = floorf(py);
    float lx = px - x0, ly = py - y0;
    int xi = (int)x0;
    int yi = (int)y0;
    float wx = (xi == 0) ? (1.f - lx) : ((xi == -1) ? lx : 0.f);
    if (wx != 0.f) {                         // wave-uniform branch
      float s = 0.f;
      if (yi >= 0 && yi < 4096)  s += (1.f - ly) * b2f(v2[vbase + (size_t)yi * 512]);
      if (yi >= -1 && yi < 4095) s += ly * b2f(v2[vbase + (size_t)(yi + 1) * 512]);
      acc += w[p] * rs * wx * s;
    }
  }
  outp[(size_t)m * 512 + h * 64 + lane] = f2b(acc);
}

// =========================================================================
extern "C" void kernel_launch(void* const* d_in, const int* in_sizes, int n_in,
                              void* d_out, int out_size, void* d_ws, size_t ws_size,
                              hipStream_t stream)
{
  if (n_in < 27) return;
  const float* x       = (const float*)d_in[0];
  const float* gn_g    = (const float*)d_in[1];
  const float* gn_b    = (const float*)d_in[2];
  const float* pin_w   = (const float*)d_in[3];
  const float* pin_b   = (const float*)d_in[4];
  const float* ln1_g   = (const float*)d_in[5];
  const float* ln1_b   = (const float*)d_in[6];
  const float* vproj_w = (const float*)d_in[7];
  const float* vproj_b = (const float*)d_in[8];
  const float* mvp_w   = (const float*)d_in[9];
  const float* mvp_b   = (const float*)d_in[10];
  const float* soff_w  = (const float*)d_in[11];
  const float* soff_b  = (const float*)d_in[12];
  const float* attw_w  = (const float*)d_in[13];
  const float* attw_b  = (const float*)d_in[14];
  const float* mop_w   = (const float*)d_in[15];
  const float* mop_b   = (const float*)d_in[16];
  const float* dout_w  = (const float*)d_in[17];
  const float* dout_b  = (const float*)d_in[18];
  const float* ln3_g   = (const float*)d_in[19];
  const float* ln3_b   = (const float*)d_in[20];
  const float* geglu_w = (const float*)d_in[21];
  const float* geglu_b = (const float*)d_in[22];
  const float* dense_w = (const float*)d_in[23];
  const float* dense_b = (const float*)d_in[24];
  const float* pout_w  = (const float*)d_in[25];
  const float* pout_b  = (const float*)d_in[26];
  float* out = (float*)d_out;

  char* ws = (char*)d_ws;
  size_t off = 0;
  auto alloc = [&](size_t bytes) -> char* {
    off = (off + 255) & ~(size_t)255;
    char* p = ws + off;
    off += bytes;
    return p;
  };
  // persistent weights (bf16, transposed)
  bf16* wtPin   = (bf16*)alloc(512 * 512 * 2);
  bf16* wtBig   = (bf16*)alloc(768 * 512 * 2);     // [vproj 512 | soff 128 | attw 64 | pad 64]
  bf16* wtMvp   = (bf16*)alloc(512 * 512 * 2);
  bf16* wtMop   = (bf16*)alloc(512 * 512 * 2);
  bf16* wtDout  = (bf16*)alloc(512 * 512 * 2);
  bf16* wtPout  = (bf16*)alloc(512 * 512 * 2);
  bf16* wtGeglu = (bf16*)alloc((size_t)4096 * 512 * 2);   // granule-16 interleaved
  bf16* wtDense = (bf16*)alloc((size_t)512 * 2048 * 2);
  float* biasBig = (float*)alloc(768 * 4);
  float* stats   = (float*)alloc(64 * 4);
  // activation regions with liveness-checked unions
  char* A  = alloc(32 * MB);  // t32 (early) | hn@0 (16MB) + t3@16MB
  char* Cg = alloc(32 * MB);  // t2 (fp32)
  char* D  = alloc(64 * MB);  // xnt@0, v@16, v2@32, msda@48
  char* E  = alloc(64 * MB);  // q16@0, sa32@16 (16MB), m2@32 (16MB) | ffin@0 (64MB)
  if (off > ws_size) return;  // workspace too small — fail loudly (zero output)

  float* t32   = (float*)A;
  bf16*  hn    = (bf16*)A;
  bf16*  t3    = (bf16*)(A + 16 * MB);
  float* t2    = (float*)Cg;
  bf16*  xnt   = (bf16*)D;
  bf16*  v16   = (bf16*)(D + 16 * MB);
  bf16*  v2b   = (bf16*)(D + 32 * MB);
  bf16*  msda  = (bf16*)(D + 48 * MB);
  bf16*  q16   = (bf16*)E;
  float* sa32  = (float*)(E + 16 * MB);
  bf16*  m2    = (bf16*)(E + 32 * MB);
  bf16*  ffin  = (bf16*)E;

  hipMemsetAsync(stats, 0, 64 * 4, stream);
  pack_bias_big<<<3, 256, 0, stream>>>(vproj_b, soff_b, attw_b, biasBig);

  // fused transpose: 11 jobs
  TransJobs J{};
  auto setJob = [&](int j, const float* src, bf16* dst, int K, int N, int Npad,
                    int ss, int sc, int a, int b) {
    J.src[j] = src; J.dst[j] = dst; J.K[j] = K; J.N[j] = N;
    J.srcStride[j] = ss; J.srcColOff[j] = sc; J.a[j] = a; J.b[j] = b;
    J.tileStart[j + 1] = J.tileStart[j] + (K / 32) * (Npad / 32);
  };
  J.tileStart[0] = 0;
  setJob(0,  pin_w,   wtPin,   512, 512,  512,  512,  0,    1, 0);
  setJob(1,  vproj_w, wtBig,   512, 512,  512,  512,  0,    1, 0);
  setJob(2,  soff_w,  wtBig,   512, 128,  128,  128,  0,    1, 512);
  setJob(3,  attw_w,  wtBig,   512, 64,   128,  64,   0,    1, 640);
  setJob(4,  mvp_w,   wtMvp,   512, 512,  512,  512,  0,    1, 0);
  setJob(5,  mop_w,   wtMop,   512, 512,  512,  512,  0,    1, 0);
  setJob(6,  dout_w,  wtDout,  512, 512,  512,  512,  0,    1, 0);
  setJob(7,  pout_w,  wtPout,  512, 512,  512,  512,  0,    1, 0);
  setJob(8,  geglu_w, wtGeglu, 512, 2048, 2048, 4096, 0,    2, 0);  // a-half
  setJob(9,  geglu_w, wtGeglu, 512, 2048, 2048, 4096, 2048, 2, 1);  // gate-half
  setJob(10, dense_w, wtDense, 2048, 512, 512,  512,  0,    1, 0);
  transpose_all<<<J.tileStart[11], dim3(32, 8), 0, stream>>>(J);

  dim3 tb(32, 8);
  gn_partial<<<512, 256, 0, stream>>>(x, stats);
  gn_apply_t<<<dim3(128, 16, 4), tb, 0, stream>>>(x, stats, gn_g, gn_b, xnt);

  // t = xnt @ pin + b   (fp32 trunk)
  gemm_bt<float, float, 0><<<dim3(4, 256), 256, 0, stream>>>(
      xnt, wtPin, pin_b, nullptr, t32, nullptr, M_, 512, 512);
  // q = LN1(t)
  layernorm_k<<<4096, 256, 0, stream>>>(t32, ln1_g, ln1_b, q16);
  // fused: value = q @ vproj (bf16) ; sa = q @ [soff|attw] (fp32)
  gemm_bt<bf16, float, 4><<<dim3(6, 256), 256, 0, stream>>>(
      q16, wtBig, biasBig, nullptr, v16, sa32, M_, 768, 512);
  // v2 = value @ mvp
  gemm_bt<bf16, float, 0><<<dim3(4, 256), 256, 0, stream>>>(
      v16, wtMvp, mvp_b, nullptr, v2b, nullptr, M_, 512, 512);
  msda_k<<<32768, 256, 0, stream>>>(sa32, v2b, msda);
  // m2 = msda @ mop + b + q ; t2 = m2 @ dout + b + t (fp32 trunk)
  gemm_bt<bf16, bf16, 1><<<dim3(4, 256), 256, 0, stream>>>(
      msda, wtMop, mop_b, q16, m2, nullptr, M_, 512, 512);
  gemm_bt<float, float, 1><<<dim3(4, 256), 256, 0, stream>>>(
      m2, wtDout, dout_b, t32, t2, nullptr, M_, 512, 512);
  // hn = LN3(t2)
  layernorm_k<<<4096, 256, 0, stream>>>(t2, ln3_g, ln3_b, hn);
  // ffin = (hn @ Wa + ba) * gelu(hn @ Wg + bg)   — interleaved GEGLU, N=4096
  gemm_geglu2<<<dim3(32, 256), 256, 0, stream>>>(hn, wtGeglu, geglu_b, ffin, 512);
  // t3 = ffin @ dense + b + t2
  gemm_bt<bf16, float, 1><<<dim3(4, 256), 256, 0, stream>>>(
      ffin, wtDense, dense_b, t2, t3, nullptr, M_, 512, 2048);
  // out[b,c,l] = (t3 @ pout + b)[b,l,c] + x[b,c,l]   (fused transpose epilogue)
  gemm_bt<float, float, 3><<<dim3(4, 256), 256, 0, stream>>>(
      t3, wtPout, pout_b, x, out, nullptr, M_, 512, 512);
}

// Round 7
// 555.967 us; speedup vs baseline: 1.1921x; 1.0120x over previous
//
#include <hip/hip_runtime.h>
#include <hip/hip_bf16.h>
#include <math.h>

using bf16 = __hip_bfloat16;
typedef __attribute__((ext_vector_type(8))) short short8;
typedef __attribute__((ext_vector_type(4))) float f32x4;

static constexpr int B_ = 4, C_ = 512, L_ = 4096, M_ = 16384;
static constexpr size_t MB = 1ull << 20;

__device__ __forceinline__ float b2f(bf16 v){ return __bfloat162float(v); }
__device__ __forceinline__ bf16  f2b(float v){ return __float2bfloat16(v); }

// async global -> LDS, 16B per lane, lane l lands at (wave-uniform base) + l*16
__device__ __forceinline__ void gl_lds16(const bf16* g, bf16* l) {
  __builtin_amdgcn_global_load_lds(
      (const __attribute__((address_space(1))) unsigned int*)g,
      (__attribute__((address_space(3))) unsigned int*)l, 16, 0, 0);
}

// gelu(g) = 0.5 g (1 + erf(g/sqrt2)); erf via A&S 7.1.26 (|eps| < 1.5e-7)
__device__ __forceinline__ float fast_gelu(float g) {
  float t  = g * 0.70710678118654752f;
  float at = fabsf(t);
  float k  = 1.f / (1.f + 0.3275911f * at);
  float poly = k * (0.254829592f + k * (-0.284496736f + k * (1.421413741f +
               k * (-1.453152027f + k * 1.061405429f))));
  float erfv = 1.f - poly * __expf(-at * at);
  erfv = __builtin_copysignf(erfv, t);
  return 0.5f * g * (1.f + erfv);
}

// ---------------- fused weight transpose: 11 jobs in one dispatch ----------
// mode a==1: dst row = n + b.  mode a==2: granule-16 geglu interleave:
//   dst row = ((n>>4)<<5) + b*16 + (n&15)   (b=0: a-half, b=1: gate-half)
struct TransJobs {
  const float* src[11];
  bf16* dst[11];
  int K[11], N[11], srcStride[11], srcColOff[11], a[11], b[11];
  int tileStart[12];
};

__global__ __launch_bounds__(256) void transpose_all(TransJobs J)
{
  __shared__ float tile[32][33];
  int t = blockIdx.x;
  int j = 0;
  #pragma unroll
  for (int q = 0; q < 10; q++) if (t >= J.tileStart[q + 1]) j = q + 1;
  t -= J.tileStart[j];
  const int kTiles = J.K[j] >> 5;
  const int k0 = (t % kTiles) * 32, n0 = (t / kTiles) * 32;
  const int tx = threadIdx.x, ty = threadIdx.y;
  const float* src = J.src[j];
  const int N = J.N[j], ss = J.srcStride[j], sc = J.srcColOff[j];
  #pragma unroll
  for (int i = 0; i < 32; i += 8) {
    int k = k0 + ty + i, n = n0 + tx;
    tile[ty + i][tx] = (n < N) ? src[(size_t)k * ss + sc + n] : 0.f;
  }
  __syncthreads();
  bf16* dst = J.dst[j];
  const int a = J.a[j], b = J.b[j], K = J.K[j];
  #pragma unroll
  for (int i = 0; i < 32; i += 8) {
    int n = n0 + ty + i, k = k0 + tx;
    int row = (a == 2) ? (((n >> 4) << 5) + b * 16 + (n & 15)) : (n + b);
    dst[(size_t)row * K + k] = f2b(tile[tx][ty + i]);
  }
}

// combined bias [vproj(512) | soff(128) | attw(64) | zero(64)]
__global__ void pack_bias_big(const float* __restrict__ vb,
    const float* __restrict__ sb, const float* __restrict__ ab,
    float* __restrict__ bp){
  int i = blockIdx.x * 256 + threadIdx.x;   // 768 threads
  float v = 0.f;
  if (i < 512) v = vb[i];
  else if (i < 640) v = sb[i - 512];
  else if (i < 704) v = ab[i - 640];
  bp[i] = v;
}

// ---------------- GroupNorm stats (sum, sumsq per (b,g)) ----------------
__global__ __launch_bounds__(256) void gn_partial(const float* __restrict__ x,
                                                  float* __restrict__ stats)
{
  int bg = blockIdx.x >> 4;
  int sc = blockIdx.x & 15;
  size_t base = (size_t)bg * 262144 + (size_t)sc * 16384;
  int tid = threadIdx.x;
  float s = 0.f, s2 = 0.f;
  #pragma unroll
  for (int i = 0; i < 8; i++) {
    size_t o = base + ((size_t)i * 256 + tid) * 8;
    float4 a = *reinterpret_cast<const float4*>(&x[o]);
    float4 b = *reinterpret_cast<const float4*>(&x[o + 4]);
    s  += a.x + a.y + a.z + a.w + b.x + b.y + b.z + b.w;
    s2 += a.x*a.x + a.y*a.y + a.z*a.z + a.w*a.w
        + b.x*b.x + b.y*b.y + b.z*b.z + b.w*b.w;
  }
  #pragma unroll
  for (int o = 32; o; o >>= 1) { s += __shfl_xor(s, o, 64); s2 += __shfl_xor(s2, o, 64); }
  __shared__ float ls[4], ls2[4];
  int wave = tid >> 6, lane = tid & 63;
  if (lane == 0) { ls[wave] = s; ls2[wave] = s2; }
  __syncthreads();
  if (tid == 0) {
    atomicAdd(&stats[bg * 2 + 0], ls[0] + ls[1] + ls[2] + ls[3]);
    atomicAdd(&stats[bg * 2 + 1], ls2[0] + ls2[1] + ls2[2] + ls2[3]);
  }
}

// ---------------- GN apply + transpose (B,C,L) -> (B*L, C) bf16 ----------
__global__ __launch_bounds__(256) void gn_apply_t(const float* __restrict__ x,
    const float* __restrict__ stats, const float* __restrict__ gg,
    const float* __restrict__ gb, bf16* __restrict__ xnt)
{
  __shared__ float tile[32][33];
  int b = blockIdx.z, c0 = blockIdx.y * 32, l0 = blockIdx.x * 32;
  int tx = threadIdx.x, ty = threadIdx.y;
  #pragma unroll
  for (int i = 0; i < 32; i += 8) {
    int c = c0 + ty + i, l = l0 + tx;
    int grp = b * 8 + (c >> 6);
    float sum = stats[grp * 2], ss = stats[grp * 2 + 1];
    float mu = sum * (1.f / 262144.f);
    float inv = rsqrtf(ss * (1.f / 262144.f) - mu * mu + 1e-5f);
    float v = x[((size_t)b * 512 + c) * 4096 + l];
    tile[ty + i][tx] = (v - mu) * inv * gg[c] + gb[c];
  }
  __syncthreads();
  #pragma unroll
  for (int i = 0; i < 32; i += 8) {
    int l = l0 + ty + i, c = c0 + tx;
    xnt[((size_t)b * 4096 + l) * 512 + c] = f2b(tile[tx][ty + i]);
  }
}

// ---------------- LayerNorm over C=512: fp32 in, bf16 out, 1 wave/row -----
__global__ __launch_bounds__(256) void layernorm_k(const float* __restrict__ X,
    const float* __restrict__ g, const float* __restrict__ b, bf16* __restrict__ Y)
{
  int row = blockIdx.x * 4 + (threadIdx.x >> 6);
  int lane = threadIdx.x & 63;
  const float* xr = X + (size_t)row * 512 + lane * 8;
  float4 a = *reinterpret_cast<const float4*>(xr);
  float4 c = *reinterpret_cast<const float4*>(xr + 4);
  float v[8] = {a.x, a.y, a.z, a.w, c.x, c.y, c.z, c.w};
  float s = 0.f, s2 = 0.f;
  #pragma unroll
  for (int i = 0; i < 8; i++) { s += v[i]; s2 += v[i] * v[i]; }
  #pragma unroll
  for (int o = 32; o; o >>= 1) { s += __shfl_xor(s, o, 64); s2 += __shfl_xor(s2, o, 64); }
  float mu = s * (1.f / 512.f);
  float inv = rsqrtf(s2 * (1.f / 512.f) - mu * mu + 1e-5f);
  float4 g0 = *reinterpret_cast<const float4*>(&g[lane * 8]);
  float4 g1 = *reinterpret_cast<const float4*>(&g[lane * 8 + 4]);
  float4 b0 = *reinterpret_cast<const float4*>(&b[lane * 8]);
  float4 b1 = *reinterpret_cast<const float4*>(&b[lane * 8 + 4]);
  float gv[8] = {g0.x, g0.y, g0.z, g0.w, g1.x, g1.y, g1.z, g1.w};
  float bv[8] = {b0.x, b0.y, b0.z, b0.w, b1.x, b1.y, b1.z, b1.w};
  bf16 outv[8];
  #pragma unroll
  for (int i = 0; i < 8; i++) outv[i] = f2b((v[i] - mu) * inv * gv[i] + bv[i]);
  *reinterpret_cast<uint4*>(Y + (size_t)row * 512 + lane * 8) =
      *reinterpret_cast<const uint4*>(outv);
}

// ------- MFMA GEMM, 64x128 tile, BK=64 (full 128B lines) + XOR swizzle -----
// LDS tile rows are 128 B; element granule gl of row r is stored at physical
// granule gl^(r&7). Staging source address carries the swizzle; LDS dest is
// the HW lane*16 pattern. Fragment reads use p=((ko*4+fq)^(fr&7)).
// EPI: 0 none | 1 += res[idx] | 3 transpose+residual fp32 out
// EPI 4: n0<512 -> bf16 Cv[m*512+n]; n0>=512 -> fp32 out2[m*256+n-512]
template<typename TOUT, typename TRES, int EPI>
__global__ __launch_bounds__(256) void gemm_bt(const bf16* __restrict__ A,
    const bf16* __restrict__ Bt, const float* __restrict__ bias,
    const TRES* __restrict__ res, TOUT* __restrict__ Cv,
    float* __restrict__ out2, int M, int N, int K)
{
  __shared__ alignas(16) bf16 As[2][64 * 64];
  __shared__ alignas(16) bf16 Bs[2][128 * 64];
  const int tid = threadIdx.x;
  const int m0 = blockIdx.y * 64;
  const int n0 = blockIdx.x * 128;
  const int lane = tid & 63;
  const int wave = tid >> 6;
  const int wm = (wave >> 1) * 32;
  const int wn = (wave & 1) * 64;
  const int fr = lane & 15;
  const int fq = lane >> 4;
  const int sr8 = lane >> 3;                    // row within 8-row staging group
  const int sgl = ((lane & 7) ^ sr8) * 8;       // swizzled source granule (elems)

  const bf16* gaBase = A  + (size_t)(m0 + wave * 16 + sr8) * K + sgl;
  const bf16* gbBase = Bt + (size_t)(n0 + wave * 32 + sr8) * K + sgl;

  f32x4 acc[2][4];
  #pragma unroll
  for (int i = 0; i < 2; i++)
    #pragma unroll
    for (int j = 0; j < 4; j++) acc[i][j] = (f32x4){0.f, 0.f, 0.f, 0.f};

  auto stage = [&](int buf, int kt) {
    const bf16* ga = gaBase + kt;
    const bf16* gb = gbBase + kt;
    bf16* la = &As[buf][wave * 16 * 64];
    bf16* lb = &Bs[buf][wave * 32 * 64];
    gl_lds16(ga, la);
    gl_lds16(ga + (size_t)8 * K, la + 8 * 64);
    #pragma unroll
    for (int j = 0; j < 4; j++)
      gl_lds16(gb + (size_t)(8 * j) * K, lb + 8 * j * 64);
  };

  stage(0, 0);
  int cur = 0;
  for (int kt = 0; kt < K; kt += 64) {
    __syncthreads();                            // drains stage(cur)
    if (kt + 64 < K) stage(cur ^ 1, kt + 64);   // async prefetch next tile
    #pragma unroll
    for (int ko = 0; ko < 2; ko++) {
      const int pa = ((ko * 4 + fq) ^ (fr & 7)) * 8;
      short8 af[2], bfv[4];
      #pragma unroll
      for (int mi = 0; mi < 2; mi++)
        af[mi] = *reinterpret_cast<const short8*>(&As[cur][(wm + mi * 16 + fr) * 64 + pa]);
      #pragma unroll
      for (int ni = 0; ni < 4; ni++)
        bfv[ni] = *reinterpret_cast<const short8*>(&Bs[cur][(wn + ni * 16 + fr) * 64 + pa]);
      #pragma unroll
      for (int mi = 0; mi < 2; mi++)
        #pragma unroll
        for (int ni = 0; ni < 4; ni++)
          acc[mi][ni] = __builtin_amdgcn_mfma_f32_16x16x32_bf16(af[mi], bfv[ni],
                                                                acc[mi][ni], 0, 0, 0);
    }
    cur ^= 1;
  }

  // epilogue: C/D layout col = lane&15, row = (lane>>4)*4 + reg
  #pragma unroll
  for (int ni = 0; ni < 4; ni++) {
    int n = n0 + wn + ni * 16 + fr;
    float bv = bias[n];
    #pragma unroll
    for (int mi = 0; mi < 2; mi++) {
      int mbase = m0 + wm + mi * 16 + fq * 4;
      if (EPI == 3) {
        int b = mbase >> 12, l = mbase & 4095;
        size_t o = ((size_t)(b * 512 + n) << 12) + l;
        float4 xr = *reinterpret_cast<const float4*>(&((const float*)res)[o]);
        float4 vv;
        vv.x = acc[mi][ni][0] + bv + xr.x;
        vv.y = acc[mi][ni][1] + bv + xr.y;
        vv.z = acc[mi][ni][2] + bv + xr.z;
        vv.w = acc[mi][ni][3] + bv + xr.w;
        *reinterpret_cast<float4*>(&((float*)Cv)[o]) = vv;
      } else if (EPI == 4) {
        #pragma unroll
        for (int r = 0; r < 4; r++) {
          float v = acc[mi][ni][r] + bv;
          if (n0 < 512) ((bf16*)Cv)[(size_t)(mbase + r) * 512 + n] = f2b(v);
          else          out2[(size_t)(mbase + r) * 256 + (n - 512)] = v;
        }
      } else {
        #pragma unroll
        for (int r = 0; r < 4; r++) {
          size_t idx = (size_t)(mbase + r) * N + n;
          float v = acc[mi][ni][r] + bv;
          if (EPI == 1) {
            float rv;
            if constexpr (sizeof(TRES) == 2) rv = b2f(((const bf16*)res)[idx]);
            else                             rv = ((const float*)res)[idx];
            v += rv;
          }
          if constexpr (sizeof(TOUT) == 2) ((bf16*)Cv)[idx] = f2b(v);
          else                             ((float*)Cv)[idx] = v;
        }
      }
    }
  }
}

// --- GEGLU GEMM, granule-16 N-interleave + BK=64 K-swizzle ----------------
// Wt rows 32j..32j+15 = Wa cols 16j..16j+15; rows 32j+16..32j+31 = Wg same.
// a and g land in the SAME lane: acc[mi][2p]=a, acc[mi][2p+1]=g.
__global__ __launch_bounds__(256) void gemm_geglu2(const bf16* __restrict__ A,
    const bf16* __restrict__ Wt, const float* __restrict__ gb,
    bf16* __restrict__ Cv, int K)
{
  __shared__ alignas(16) bf16 As[2][64 * 64];
  __shared__ alignas(16) bf16 Bs[2][128 * 64];
  const int tid = threadIdx.x;
  const int m0 = blockIdx.y * 64;
  const int n0 = blockIdx.x * 128;       // interleaved-row space (0..4095)
  const int lane = tid & 63;
  const int wave = tid >> 6;
  const int wm = (wave >> 1) * 32;
  const int wn = (wave & 1) * 64;
  const int fr = lane & 15;
  const int fq = lane >> 4;
  const int sr8 = lane >> 3;
  const int sgl = ((lane & 7) ^ sr8) * 8;

  const bf16* gaBase = A  + (size_t)(m0 + wave * 16 + sr8) * K + sgl;
  const bf16* gbBase = Wt + (size_t)(n0 + wave * 32 + sr8) * K + sgl;

  f32x4 acc[2][4];
  #pragma unroll
  for (int i = 0; i < 2; i++)
    #pragma unroll
    for (int j = 0; j < 4; j++) acc[i][j] = (f32x4){0.f, 0.f, 0.f, 0.f};

  auto stage = [&](int buf, int kt) {
    const bf16* ga = gaBase + kt;
    const bf16* gb2 = gbBase + kt;
    bf16* la = &As[buf][wave * 16 * 64];
    bf16* lb = &Bs[buf][wave * 32 * 64];
    gl_lds16(ga, la);
    gl_lds16(ga + (size_t)8 * K, la + 8 * 64);
    #pragma unroll
    for (int j = 0; j < 4; j++)
      gl_lds16(gb2 + (size_t)(8 * j) * K, lb + 8 * j * 64);
  };

  stage(0, 0);
  int cur = 0;
  for (int kt = 0; kt < K; kt += 64) {
    __syncthreads();
    if (kt + 64 < K) stage(cur ^ 1, kt + 64);
    #pragma unroll
    for (int ko = 0; ko < 2; ko++) {
      const int pa = ((ko * 4 + fq) ^ (fr & 7)) * 8;
      short8 af[2], bfv[4];
      #pragma unroll
      for (int mi = 0; mi < 2; mi++)
        af[mi] = *reinterpret_cast<const short8*>(&As[cur][(wm + mi * 16 + fr) * 64 + pa]);
      #pragma unroll
      for (int ni = 0; ni < 4; ni++)
        bfv[ni] = *reinterpret_cast<const short8*>(&Bs[cur][(wn + ni * 16 + fr) * 64 + pa]);
      #pragma unroll
      for (int mi = 0; mi < 2; mi++)
        #pragma unroll
        for (int ni = 0; ni < 4; ni++)
          acc[mi][ni] = __builtin_amdgcn_mfma_f32_16x16x32_bf16(af[mi], bfv[ni],
                                                                acc[mi][ni], 0, 0, 0);
    }
    cur ^= 1;
  }

  const int cbase = (n0 + wn) >> 1;
  #pragma unroll
  for (int pi = 0; pi < 2; pi++) {
    int col = cbase + pi * 16 + fr;
    float ba = gb[col];
    float bg = gb[2048 + col];
    #pragma unroll
    for (int mi = 0; mi < 2; mi++) {
      int mbase = m0 + wm + mi * 16 + fq * 4;
      #pragma unroll
      for (int r = 0; r < 4; r++) {
        float a = acc[mi][2 * pi][r] + ba;
        float g = acc[mi][2 * pi + 1][r] + bg;
        Cv[(size_t)(mbase + r) * 2048 + col] = f2b(a * fast_gelu(g));
      }
    }
  }
}

// ---------------- MSDA: degenerate deformable attention (Hl=L, Wl=1) ------
// sa: [M][256] fp32: cols 0..127 = sampling offsets, 128..191 = attn logits
__global__ __launch_bounds__(256) void msda_k(const float* __restrict__ sa,
    const bf16* __restrict__ v2, bf16* __restrict__ outp)
{
  int unit = blockIdx.x * 4 + (threadIdx.x >> 6);  // (b*L+l)*8 + h
  int lane = threadIdx.x & 63;
  int m = unit >> 3;
  int h = unit & 7;
  int b = m >> 12;                                  // L = 4096
  const float* lg = &sa[(size_t)m * 256 + 128 + h * 8];
  float w[8], mx = -1e30f;
  #pragma unroll
  for (int p = 0; p < 8; p++) { w[p] = lg[p]; mx = fmaxf(mx, w[p]); }
  float sum = 0.f;
  #pragma unroll
  for (int p = 0; p < 8; p++) { w[p] = expf(w[p] - mx); sum += w[p]; }
  float rs = 1.f / sum;
  const float* op = &sa[(size_t)m * 256 + h * 16];
  size_t vbase = ((size_t)b * 4096) * 512 + h * 64 + lane;
  float acc = 0.f;
  #pragma unroll
  for (int p = 0; p < 8; p++) {
    float ox = op[p * 2 + 0], oy = op[p * 2 + 1];
    float gx = 2.f * (0.5f + ox) - 1.f;
    float px = ((gx + 1.f) * 1.f - 1.f) * 0.5f;              // = ox (mirrors ref fp ops)
    float gy = 2.f * (0.5f + oy * (1.f / 4096.f)) - 1.f;
    float py = ((gy + 1.f) * 4096.f - 1.f) * 0.5f;           // = oy + 2047.5
    float x0 = floorf(px), y0 = floorf(py);
    float lx = px - x0, ly = py - y0;
    int xi = (int)x0;
    int yi = (int)y0;
    float wx = (xi == 0) ? (1.f - lx) : ((xi == -1) ? lx : 0.f);
    if (wx != 0.f) {                         // wave-uniform branch
      float s = 0.f;
      if (yi >= 0 && yi < 4096)  s += (1.f - ly) * b2f(v2[vbase + (size_t)yi * 512]);
      if (yi >= -1 && yi < 4095) s += ly * b2f(v2[vbase + (size_t)(yi + 1) * 512]);
      acc += w[p] * rs * wx * s;
    }
  }
  outp[(size_t)m * 512 + h * 64 + lane] = f2b(acc);
}

// =========================================================================
extern "C" void kernel_launch(void* const* d_in, const int* in_sizes, int n_in,
                              void* d_out, int out_size, void* d_ws, size_t ws_size,
                              hipStream_t stream)
{
  if (n_in < 27) return;
  const float* x       = (const float*)d_in[0];
  const float* gn_g    = (const float*)d_in[1];
  const float* gn_b    = (const float*)d_in[2];
  const float* pin_w   = (const float*)d_in[3];
  const float* pin_b   = (const float*)d_in[4];
  const float* ln1_g   = (const float*)d_in[5];
  const float* ln1_b   = (const float*)d_in[6];
  const float* vproj_w = (const float*)d_in[7];
  const float* vproj_b = (const float*)d_in[8];
  const float* mvp_w   = (const float*)d_in[9];
  const float* mvp_b   = (const float*)d_in[10];
  const float* soff_w  = (const float*)d_in[11];
  const float* soff_b  = (const float*)d_in[12];
  const float* attw_w  = (const float*)d_in[13];
  const float* attw_b  = (const float*)d_in[14];
  const float* mop_w   = (const float*)d_in[15];
  const float* mop_b   = (const float*)d_in[16];
  const float* dout_w  = (const float*)d_in[17];
  const float* dout_b  = (const float*)d_in[18];
  const float* ln3_g   = (const float*)d_in[19];
  const float* ln3_b   = (const float*)d_in[20];
  const float* geglu_w = (const float*)d_in[21];
  const float* geglu_b = (const float*)d_in[22];
  const float* dense_w = (const float*)d_in[23];
  const float* dense_b = (const float*)d_in[24];
  const float* pout_w  = (const float*)d_in[25];
  const float* pout_b  = (const float*)d_in[26];
  float* out = (float*)d_out;

  char* ws = (char*)d_ws;
  size_t off = 0;
  auto alloc = [&](size_t bytes) -> char* {
    off = (off + 255) & ~(size_t)255;
    char* p = ws + off;
    off += bytes;
    return p;
  };
  // persistent weights (bf16, transposed)
  bf16* wtPin   = (bf16*)alloc(512 * 512 * 2);
  bf16* wtBig   = (bf16*)alloc(768 * 512 * 2);     // [vproj 512 | soff 128 | attw 64 | pad 64]
  bf16* wtMvp   = (bf16*)alloc(512 * 512 * 2);
  bf16* wtMop   = (bf16*)alloc(512 * 512 * 2);
  bf16* wtDout  = (bf16*)alloc(512 * 512 * 2);
  bf16* wtPout  = (bf16*)alloc(512 * 512 * 2);
  bf16* wtGeglu = (bf16*)alloc((size_t)4096 * 512 * 2);   // granule-16 interleaved
  bf16* wtDense = (bf16*)alloc((size_t)512 * 2048 * 2);
  float* biasBig = (float*)alloc(768 * 4);
  float* stats   = (float*)alloc(64 * 4);
  // activation regions with liveness-checked unions
  char* A  = alloc(32 * MB);  // t32 (early) | hn@0 (16MB) + t3@16MB
  char* Cg = alloc(32 * MB);  // t2 (fp32)
  char* D  = alloc(64 * MB);  // xnt@0, v@16, v2@32, msda@48
  char* E  = alloc(64 * MB);  // q16@0, sa32@16 (16MB), m2@32 (16MB) | ffin@0 (64MB)
  if (off > ws_size) return;  // workspace too small — fail loudly (zero output)

  float* t32   = (float*)A;
  bf16*  hn    = (bf16*)A;
  bf16*  t3    = (bf16*)(A + 16 * MB);
  float* t2    = (float*)Cg;
  bf16*  xnt   = (bf16*)D;
  bf16*  v16   = (bf16*)(D + 16 * MB);
  bf16*  v2b   = (bf16*)(D + 32 * MB);
  bf16*  msda  = (bf16*)(D + 48 * MB);
  bf16*  q16   = (bf16*)E;
  float* sa32  = (float*)(E + 16 * MB);
  bf16*  m2    = (bf16*)(E + 32 * MB);
  bf16*  ffin  = (bf16*)E;

  hipMemsetAsync(stats, 0, 64 * 4, stream);
  pack_bias_big<<<3, 256, 0, stream>>>(vproj_b, soff_b, attw_b, biasBig);

  // fused transpose: 11 jobs
  TransJobs J{};
  auto setJob = [&](int j, const float* src, bf16* dst, int K, int N, int Npad,
                    int ss, int sc, int a, int b) {
    J.src[j] = src; J.dst[j] = dst; J.K[j] = K; J.N[j] = N;
    J.srcStride[j] = ss; J.srcColOff[j] = sc; J.a[j] = a; J.b[j] = b;
    J.tileStart[j + 1] = J.tileStart[j] + (K / 32) * (Npad / 32);
  };
  J.tileStart[0] = 0;
  setJob(0,  pin_w,   wtPin,   512, 512,  512,  512,  0,    1, 0);
  setJob(1,  vproj_w, wtBig,   512, 512,  512,  512,  0,    1, 0);
  setJob(2,  soff_w,  wtBig,   512, 128,  128,  128,  0,    1, 512);
  setJob(3,  attw_w,  wtBig,   512, 64,   128,  64,   0,    1, 640);
  setJob(4,  mvp_w,   wtMvp,   512, 512,  512,  512,  0,    1, 0);
  setJob(5,  mop_w,   wtMop,   512, 512,  512,  512,  0,    1, 0);
  setJob(6,  dout_w,  wtDout,  512, 512,  512,  512,  0,    1, 0);
  setJob(7,  pout_w,  wtPout,  512, 512,  512,  512,  0,    1, 0);
  setJob(8,  geglu_w, wtGeglu, 512, 2048, 2048, 4096, 0,    2, 0);  // a-half
  setJob(9,  geglu_w, wtGeglu, 512, 2048, 2048, 4096, 2048, 2, 1);  // gate-half
  setJob(10, dense_w, wtDense, 2048, 512, 512,  512,  0,    1, 0);
  transpose_all<<<J.tileStart[11], dim3(32, 8), 0, stream>>>(J);

  dim3 tb(32, 8);
  gn_partial<<<512, 256, 0, stream>>>(x, stats);
  gn_apply_t<<<dim3(128, 16, 4), tb, 0, stream>>>(x, stats, gn_g, gn_b, xnt);

  // t = xnt @ pin + b   (fp32 trunk)
  gemm_bt<float, float, 0><<<dim3(4, 256), 256, 0, stream>>>(
      xnt, wtPin, pin_b, nullptr, t32, nullptr, M_, 512, 512);
  // q = LN1(t)
  layernorm_k<<<4096, 256, 0, stream>>>(t32, ln1_g, ln1_b, q16);
  // fused: value = q @ vproj (bf16) ; sa = q @ [soff|attw] (fp32)
  gemm_bt<bf16, float, 4><<<dim3(6, 256), 256, 0, stream>>>(
      q16, wtBig, biasBig, nullptr, v16, sa32, M_, 768, 512);
  // v2 = value @ mvp
  gemm_bt<bf16, float, 0><<<dim3(4, 256), 256, 0, stream>>>(
      v16, wtMvp, mvp_b, nullptr, v2b, nullptr, M_, 512, 512);
  msda_k<<<32768, 256, 0, stream>>>(sa32, v2b, msda);
  // m2 = msda @ mop + b + q ; t2 = m2 @ dout + b + t (fp32 trunk)
  gemm_bt<bf16, bf16, 1><<<dim3(4, 256), 256, 0, stream>>>(
      msda, wtMop, mop_b, q16, m2, nullptr, M_, 512, 512);
  gemm_bt<float, float, 1><<<dim3(4, 256), 256, 0, stream>>>(
      m2, wtDout, dout_b, t32, t2, nullptr, M_, 512, 512);
  // hn = LN3(t2)
  layernorm_k<<<4096, 256, 0, stream>>>(t2, ln3_g, ln3_b, hn);
  // ffin = (hn @ Wa + ba) * gelu(hn @ Wg + bg)   — interleaved GEGLU, N=4096
  gemm_geglu2<<<dim3(32, 256), 256, 0, stream>>>(hn, wtGeglu, geglu_b, ffin, 512);
  // t3 = ffin @ dense + b + t2
  gemm_bt<bf16, float, 1><<<dim3(4, 256), 256, 0, stream>>>(
      ffin, wtDense, dense_b, t2, t3, nullptr, M_, 512, 2048);
  // out[b,c,l] = (t3 @ pout + b)[b,l,c] + x[b,c,l]   (fused transpose epilogue)
  gemm_bt<float, float, 3><<<dim3(4, 256), 256, 0, stream>>>(
      t3, wtPout, pout_b, x, out, nullptr, M_, 512, 512);
}

// Round 8
// 514.000 us; speedup vs baseline: 1.2895x; 1.0816x over previous
//
#include <hip/hip_runtime.h>
#include <hip/hip_bf16.h>
#include <math.h>

using bf16 = __hip_bfloat16;
typedef __attribute__((ext_vector_type(8))) short short8;
typedef __attribute__((ext_vector_type(4))) float f32x4;

static constexpr int B_ = 4, C_ = 512, L_ = 4096, M_ = 16384;
static constexpr size_t MB = 1ull << 20;

__device__ __forceinline__ float b2f(bf16 v){ return __bfloat162float(v); }
__device__ __forceinline__ bf16  f2b(float v){ return __float2bfloat16(v); }

// async global -> LDS, 16B per lane, lane l lands at (wave-uniform base) + l*16
__device__ __forceinline__ void gl_lds16(const bf16* g, bf16* l) {
  __builtin_amdgcn_global_load_lds(
      (const __attribute__((address_space(1))) unsigned int*)g,
      (__attribute__((address_space(3))) unsigned int*)l, 16, 0, 0);
}

// gelu(g) = 0.5 g (1 + erf(g/sqrt2)); erf via A&S 7.1.26 (|eps| < 1.5e-7)
__device__ __forceinline__ float fast_gelu(float g) {
  float t  = g * 0.70710678118654752f;
  float at = fabsf(t);
  float k  = 1.f / (1.f + 0.3275911f * at);
  float poly = k * (0.254829592f + k * (-0.284496736f + k * (1.421413741f +
               k * (-1.453152027f + k * 1.061405429f))));
  float erfv = 1.f - poly * __expf(-at * at);
  erfv = __builtin_copysignf(erfv, t);
  return 0.5f * g * (1.f + erfv);
}

// ---------------- fused weight transpose: 11 jobs in one dispatch ----------
// mode a==1: dst row = n + b.  mode a==2: granule-16 geglu interleave:
//   dst row = ((n>>4)<<5) + b*16 + (n&15)   (b=0: a-half, b=1: gate-half)
struct TransJobs {
  const float* src[11];
  bf16* dst[11];
  int K[11], N[11], srcStride[11], srcColOff[11], a[11], b[11];
  int tileStart[12];
};

__global__ __launch_bounds__(256) void transpose_all(TransJobs J)
{
  __shared__ float tile[32][33];
  int t = blockIdx.x;
  int j = 0;
  #pragma unroll
  for (int q = 0; q < 10; q++) if (t >= J.tileStart[q + 1]) j = q + 1;
  t -= J.tileStart[j];
  const int kTiles = J.K[j] >> 5;
  const int k0 = (t % kTiles) * 32, n0 = (t / kTiles) * 32;
  const int tx = threadIdx.x, ty = threadIdx.y;
  const float* src = J.src[j];
  const int N = J.N[j], ss = J.srcStride[j], sc = J.srcColOff[j];
  #pragma unroll
  for (int i = 0; i < 32; i += 8) {
    int k = k0 + ty + i, n = n0 + tx;
    tile[ty + i][tx] = (n < N) ? src[(size_t)k * ss + sc + n] : 0.f;
  }
  __syncthreads();
  bf16* dst = J.dst[j];
  const int a = J.a[j], b = J.b[j], K = J.K[j];
  #pragma unroll
  for (int i = 0; i < 32; i += 8) {
    int n = n0 + ty + i, k = k0 + tx;
    int row = (a == 2) ? (((n >> 4) << 5) + b * 16 + (n & 15)) : (n + b);
    dst[(size_t)row * K + k] = f2b(tile[tx][ty + i]);
  }
}

// combined bias [vproj(512) | soff(128) | attw(64) | zero(64)]
__global__ void pack_bias_big(const float* __restrict__ vb,
    const float* __restrict__ sb, const float* __restrict__ ab,
    float* __restrict__ bp){
  int i = blockIdx.x * 256 + threadIdx.x;   // 768 threads
  float v = 0.f;
  if (i < 512) v = vb[i];
  else if (i < 640) v = sb[i - 512];
  else if (i < 704) v = ab[i - 640];
  bp[i] = v;
}

// ---------------- GroupNorm stats (sum, sumsq per (b,g)) ----------------
__global__ __launch_bounds__(256) void gn_partial(const float* __restrict__ x,
                                                  float* __restrict__ stats)
{
  int bg = blockIdx.x >> 4;
  int sc = blockIdx.x & 15;
  size_t base = (size_t)bg * 262144 + (size_t)sc * 16384;
  int tid = threadIdx.x;
  float s = 0.f, s2 = 0.f;
  #pragma unroll
  for (int i = 0; i < 8; i++) {
    size_t o = base + ((size_t)i * 256 + tid) * 8;
    float4 a = *reinterpret_cast<const float4*>(&x[o]);
    float4 b = *reinterpret_cast<const float4*>(&x[o + 4]);
    s  += a.x + a.y + a.z + a.w + b.x + b.y + b.z + b.w;
    s2 += a.x*a.x + a.y*a.y + a.z*a.z + a.w*a.w
        + b.x*b.x + b.y*b.y + b.z*b.z + b.w*b.w;
  }
  #pragma unroll
  for (int o = 32; o; o >>= 1) { s += __shfl_xor(s, o, 64); s2 += __shfl_xor(s2, o, 64); }
  __shared__ float ls[4], ls2[4];
  int wave = tid >> 6, lane = tid & 63;
  if (lane == 0) { ls[wave] = s; ls2[wave] = s2; }
  __syncthreads();
  if (tid == 0) {
    atomicAdd(&stats[bg * 2 + 0], ls[0] + ls[1] + ls[2] + ls[3]);
    atomicAdd(&stats[bg * 2 + 1], ls2[0] + ls2[1] + ls2[2] + ls2[3]);
  }
}

// ---------------- GN apply + transpose (B,C,L) -> (B*L, C) bf16 ----------
__global__ __launch_bounds__(256) void gn_apply_t(const float* __restrict__ x,
    const float* __restrict__ stats, const float* __restrict__ gg,
    const float* __restrict__ gb, bf16* __restrict__ xnt)
{
  __shared__ float tile[32][33];
  int b = blockIdx.z, c0 = blockIdx.y * 32, l0 = blockIdx.x * 32;
  int tx = threadIdx.x, ty = threadIdx.y;
  #pragma unroll
  for (int i = 0; i < 32; i += 8) {
    int c = c0 + ty + i, l = l0 + tx;
    int grp = b * 8 + (c >> 6);
    float sum = stats[grp * 2], ss = stats[grp * 2 + 1];
    float mu = sum * (1.f / 262144.f);
    float inv = rsqrtf(ss * (1.f / 262144.f) - mu * mu + 1e-5f);
    float v = x[((size_t)b * 512 + c) * 4096 + l];
    tile[ty + i][tx] = (v - mu) * inv * gg[c] + gb[c];
  }
  __syncthreads();
  #pragma unroll
  for (int i = 0; i < 32; i += 8) {
    int l = l0 + ty + i, c = c0 + tx;
    xnt[((size_t)b * 4096 + l) * 512 + c] = f2b(tile[tx][ty + i]);
  }
}

// ---------------- LayerNorm over C=512: fp32 in, bf16 out, 1 wave/row -----
__global__ __launch_bounds__(256) void layernorm_k(const float* __restrict__ X,
    const float* __restrict__ g, const float* __restrict__ b, bf16* __restrict__ Y)
{
  int row = blockIdx.x * 4 + (threadIdx.x >> 6);
  int lane = threadIdx.x & 63;
  const float* xr = X + (size_t)row * 512 + lane * 8;
  float4 a = *reinterpret_cast<const float4*>(xr);
  float4 c = *reinterpret_cast<const float4*>(xr + 4);
  float v[8] = {a.x, a.y, a.z, a.w, c.x, c.y, c.z, c.w};
  float s = 0.f, s2 = 0.f;
  #pragma unroll
  for (int i = 0; i < 8; i++) { s += v[i]; s2 += v[i] * v[i]; }
  #pragma unroll
  for (int o = 32; o; o >>= 1) { s += __shfl_xor(s, o, 64); s2 += __shfl_xor(s2, o, 64); }
  float mu = s * (1.f / 512.f);
  float inv = rsqrtf(s2 * (1.f / 512.f) - mu * mu + 1e-5f);
  float4 g0 = *reinterpret_cast<const float4*>(&g[lane * 8]);
  float4 g1 = *reinterpret_cast<const float4*>(&g[lane * 8 + 4]);
  float4 b0 = *reinterpret_cast<const float4*>(&b[lane * 8]);
  float4 b1 = *reinterpret_cast<const float4*>(&b[lane * 8 + 4]);
  float gv[8] = {g0.x, g0.y, g0.z, g0.w, g1.x, g1.y, g1.z, g1.w};
  float bv[8] = {b0.x, b0.y, b0.z, b0.w, b1.x, b1.y, b1.z, b1.w};
  bf16 outv[8];
  #pragma unroll
  for (int i = 0; i < 8; i++) outv[i] = f2b((v[i] - mu) * inv * gv[i] + bv[i]);
  *reinterpret_cast<uint4*>(Y + (size_t)row * 512 + lane * 8) =
      *reinterpret_cast<const uint4*>(outv);
}

// --- MFMA GEMM, 128x128 tile, 4x4 frags, BK=64 full-line + XOR swizzle -----
// LDS rows 128 B; granule gl of row r stored at gl^(r&7); fragment reads use
// p=((ko*4+fq)^(fr&7)). Dbuf LDS = 64 KB -> 2 blocks/CU.
// EPI: 0 none | 1 += res[idx] | 3 transpose+residual fp32 out
// EPI 4: n0<512 -> bf16 Cv[m*512+n]; n0>=512 -> fp32 out2[m*256+n-512]
template<typename TOUT, typename TRES, int EPI>
__global__ __launch_bounds__(256) void gemm_bt(const bf16* __restrict__ A,
    const bf16* __restrict__ Bt, const float* __restrict__ bias,
    const TRES* __restrict__ res, TOUT* __restrict__ Cv,
    float* __restrict__ out2, int M, int N, int K)
{
  __shared__ alignas(16) bf16 As[2][128 * 64];
  __shared__ alignas(16) bf16 Bs[2][128 * 64];
  const int tid = threadIdx.x;
  const int m0 = blockIdx.y * 128;
  const int n0 = blockIdx.x * 128;
  const int lane = tid & 63;
  const int wave = tid >> 6;
  const int wm = (wave >> 1) * 64;
  const int wn = (wave & 1) * 64;
  const int fr = lane & 15;
  const int fq = lane >> 4;
  const int sr8 = lane >> 3;                    // row within 8-row staging group
  const int sgl = ((lane & 7) ^ sr8) * 8;       // swizzled source granule (elems)

  const bf16* gaBase = A  + (size_t)(m0 + wave * 32 + sr8) * K + sgl;
  const bf16* gbBase = Bt + (size_t)(n0 + wave * 32 + sr8) * K + sgl;

  f32x4 acc[4][4];
  #pragma unroll
  for (int i = 0; i < 4; i++)
    #pragma unroll
    for (int j = 0; j < 4; j++) acc[i][j] = (f32x4){0.f, 0.f, 0.f, 0.f};

  auto stage = [&](int buf, int kt) {
    const bf16* ga = gaBase + kt;
    const bf16* gb = gbBase + kt;
    bf16* la = &As[buf][wave * 32 * 64];
    bf16* lb = &Bs[buf][wave * 32 * 64];
    #pragma unroll
    for (int j = 0; j < 4; j++) {
      gl_lds16(ga + (size_t)(8 * j) * K, la + 8 * j * 64);
      gl_lds16(gb + (size_t)(8 * j) * K, lb + 8 * j * 64);
    }
  };

  stage(0, 0);
  int cur = 0;
  for (int kt = 0; kt < K; kt += 64) {
    __syncthreads();                            // drains stage(cur)
    if (kt + 64 < K) stage(cur ^ 1, kt + 64);   // async prefetch next tile
    #pragma unroll
    for (int ko = 0; ko < 2; ko++) {
      const int pa = ((ko * 4 + fq) ^ (fr & 7)) * 8;
      short8 af[4], bfv[4];
      #pragma unroll
      for (int mi = 0; mi < 4; mi++)
        af[mi] = *reinterpret_cast<const short8*>(&As[cur][(wm + mi * 16 + fr) * 64 + pa]);
      #pragma unroll
      for (int ni = 0; ni < 4; ni++)
        bfv[ni] = *reinterpret_cast<const short8*>(&Bs[cur][(wn + ni * 16 + fr) * 64 + pa]);
      #pragma unroll
      for (int mi = 0; mi < 4; mi++)
        #pragma unroll
        for (int ni = 0; ni < 4; ni++)
          acc[mi][ni] = __builtin_amdgcn_mfma_f32_16x16x32_bf16(af[mi], bfv[ni],
                                                                acc[mi][ni], 0, 0, 0);
    }
    cur ^= 1;
  }

  // epilogue: C/D layout col = lane&15, row = (lane>>4)*4 + reg
  #pragma unroll
  for (int ni = 0; ni < 4; ni++) {
    int n = n0 + wn + ni * 16 + fr;
    float bv = bias[n];
    #pragma unroll
    for (int mi = 0; mi < 4; mi++) {
      int mbase = m0 + wm + mi * 16 + fq * 4;
      if (EPI == 3) {
        int b = mbase >> 12, l = mbase & 4095;
        size_t o = ((size_t)(b * 512 + n) << 12) + l;
        float4 xr = *reinterpret_cast<const float4*>(&((const float*)res)[o]);
        float4 vv;
        vv.x = acc[mi][ni][0] + bv + xr.x;
        vv.y = acc[mi][ni][1] + bv + xr.y;
        vv.z = acc[mi][ni][2] + bv + xr.z;
        vv.w = acc[mi][ni][3] + bv + xr.w;
        *reinterpret_cast<float4*>(&((float*)Cv)[o]) = vv;
      } else if (EPI == 4) {
        #pragma unroll
        for (int r = 0; r < 4; r++) {
          float v = acc[mi][ni][r] + bv;
          if (n0 < 512) ((bf16*)Cv)[(size_t)(mbase + r) * 512 + n] = f2b(v);
          else          out2[(size_t)(mbase + r) * 256 + (n - 512)] = v;
        }
      } else {
        #pragma unroll
        for (int r = 0; r < 4; r++) {
          size_t idx = (size_t)(mbase + r) * N + n;
          float v = acc[mi][ni][r] + bv;
          if (EPI == 1) {
            float rv;
            if constexpr (sizeof(TRES) == 2) rv = b2f(((const bf16*)res)[idx]);
            else                             rv = ((const float*)res)[idx];
            v += rv;
          }
          if constexpr (sizeof(TOUT) == 2) ((bf16*)Cv)[idx] = f2b(v);
          else                             ((float*)Cv)[idx] = v;
        }
      }
    }
  }
}

// --- GEGLU GEMM, 128x128 tile, granule-16 N-interleave + BK=64 swizzle ----
// Wt rows 32j..32j+15 = Wa cols 16j..16j+15; rows 32j+16..32j+31 = Wg same.
// a and g land in the SAME lane: acc[mi][2p]=a, acc[mi][2p+1]=g.
__global__ __launch_bounds__(256) void gemm_geglu2(const bf16* __restrict__ A,
    const bf16* __restrict__ Wt, const float* __restrict__ gb,
    bf16* __restrict__ Cv, int K)
{
  __shared__ alignas(16) bf16 As[2][128 * 64];
  __shared__ alignas(16) bf16 Bs[2][128 * 64];
  const int tid = threadIdx.x;
  const int m0 = blockIdx.y * 128;
  const int n0 = blockIdx.x * 128;       // interleaved-row space (0..4095)
  const int lane = tid & 63;
  const int wave = tid >> 6;
  const int wm = (wave >> 1) * 64;
  const int wn = (wave & 1) * 64;
  const int fr = lane & 15;
  const int fq = lane >> 4;
  const int sr8 = lane >> 3;
  const int sgl = ((lane & 7) ^ sr8) * 8;

  const bf16* gaBase = A  + (size_t)(m0 + wave * 32 + sr8) * K + sgl;
  const bf16* gbBase = Wt + (size_t)(n0 + wave * 32 + sr8) * K + sgl;

  f32x4 acc[4][4];
  #pragma unroll
  for (int i = 0; i < 4; i++)
    #pragma unroll
    for (int j = 0; j < 4; j++) acc[i][j] = (f32x4){0.f, 0.f, 0.f, 0.f};

  auto stage = [&](int buf, int kt) {
    const bf16* ga = gaBase + kt;
    const bf16* gb2 = gbBase + kt;
    bf16* la = &As[buf][wave * 32 * 64];
    bf16* lb = &Bs[buf][wave * 32 * 64];
    #pragma unroll
    for (int j = 0; j < 4; j++) {
      gl_lds16(ga + (size_t)(8 * j) * K, la + 8 * j * 64);
      gl_lds16(gb2 + (size_t)(8 * j) * K, lb + 8 * j * 64);
    }
  };

  stage(0, 0);
  int cur = 0;
  for (int kt = 0; kt < K; kt += 64) {
    __syncthreads();
    if (kt + 64 < K) stage(cur ^ 1, kt + 64);
    #pragma unroll
    for (int ko = 0; ko < 2; ko++) {
      const int pa = ((ko * 4 + fq) ^ (fr & 7)) * 8;
      short8 af[4], bfv[4];
      #pragma unroll
      for (int mi = 0; mi < 4; mi++)
        af[mi] = *reinterpret_cast<const short8*>(&As[cur][(wm + mi * 16 + fr) * 64 + pa]);
      #pragma unroll
      for (int ni = 0; ni < 4; ni++)
        bfv[ni] = *reinterpret_cast<const short8*>(&Bs[cur][(wn + ni * 16 + fr) * 64 + pa]);
      #pragma unroll
      for (int mi = 0; mi < 4; mi++)
        #pragma unroll
        for (int ni = 0; ni < 4; ni++)
          acc[mi][ni] = __builtin_amdgcn_mfma_f32_16x16x32_bf16(af[mi], bfv[ni],
                                                                acc[mi][ni], 0, 0, 0);
    }
    cur ^= 1;
  }

  const int cbase = (n0 + wn) >> 1;
  #pragma unroll
  for (int pi = 0; pi < 2; pi++) {
    int col = cbase + pi * 16 + fr;
    float ba = gb[col];
    float bg = gb[2048 + col];
    #pragma unroll
    for (int mi = 0; mi < 4; mi++) {
      int mbase = m0 + wm + mi * 16 + fq * 4;
      #pragma unroll
      for (int r = 0; r < 4; r++) {
        float a = acc[mi][2 * pi][r] + ba;
        float g = acc[mi][2 * pi + 1][r] + bg;
        Cv[(size_t)(mbase + r) * 2048 + col] = f2b(a * fast_gelu(g));
      }
    }
  }
}

// ---------------- MSDA: degenerate deformable attention (Hl=L, Wl=1) ------
// sa: [M][256] fp32: cols 0..127 = sampling offsets, 128..191 = attn logits
__global__ __launch_bounds__(256) void msda_k(const float* __restrict__ sa,
    const bf16* __restrict__ v2, bf16* __restrict__ outp)
{
  int unit = blockIdx.x * 4 + (threadIdx.x >> 6);  // (b*L+l)*8 + h
  int lane = threadIdx.x & 63;
  int m = unit >> 3;
  int h = unit & 7;
  int b = m >> 12;                                  // L = 4096
  const float* lg = &sa[(size_t)m * 256 + 128 + h * 8];
  float w[8], mx = -1e30f;
  #pragma unroll
  for (int p = 0; p < 8; p++) { w[p] = lg[p]; mx = fmaxf(mx, w[p]); }
  float sum = 0.f;
  #pragma unroll
  for (int p = 0; p < 8; p++) { w[p] = expf(w[p] - mx); sum += w[p]; }
  float rs = 1.f / sum;
  const float* op = &sa[(size_t)m * 256 + h * 16];
  size_t vbase = ((size_t)b * 4096) * 512 + h * 64 + lane;
  float acc = 0.f;
  #pragma unroll
  for (int p = 0; p < 8; p++) {
    float ox = op[p * 2 + 0], oy = op[p * 2 + 1];
    float gx = 2.f * (0.5f + ox) - 1.f;
    float px = ((gx + 1.f) * 1.f - 1.f) * 0.5f;              // = ox (mirrors ref fp ops)
    float gy = 2.f * (0.5f + oy * (1.f / 4096.f)) - 1.f;
    float py = ((gy + 1.f) * 4096.f - 1.f) * 0.5f;           // = oy + 2047.5
    float x0 = floorf(px), y0 = floorf(py);
    float lx = px - x0, ly = py - y0;
    int xi = (int)x0;
    int yi = (int)y0;
    float wx = (xi == 0) ? (1.f - lx) : ((xi == -1) ? lx : 0.f);
    if (wx != 0.f) {                         // wave-uniform branch
      float s = 0.f;
      if (yi >= 0 && yi < 4096)  s += (1.f - ly) * b2f(v2[vbase + (size_t)yi * 512]);
      if (yi >= -1 && yi < 4095) s += ly * b2f(v2[vbase + (size_t)(yi + 1) * 512]);
      acc += w[p] * rs * wx * s;
    }
  }
  outp[(size_t)m * 512 + h * 64 + lane] = f2b(acc);
}

// =========================================================================
extern "C" void kernel_launch(void* const* d_in, const int* in_sizes, int n_in,
                              void* d_out, int out_size, void* d_ws, size_t ws_size,
                              hipStream_t stream)
{
  if (n_in < 27) return;
  const float* x       = (const float*)d_in[0];
  const float* gn_g    = (const float*)d_in[1];
  const float* gn_b    = (const float*)d_in[2];
  const float* pin_w   = (const float*)d_in[3];
  const float* pin_b   = (const float*)d_in[4];
  const float* ln1_g   = (const float*)d_in[5];
  const float* ln1_b   = (const float*)d_in[6];
  const float* vproj_w = (const float*)d_in[7];
  const float* vproj_b = (const float*)d_in[8];
  const float* mvp_w   = (const float*)d_in[9];
  const float* mvp_b   = (const float*)d_in[10];
  const float* soff_w  = (const float*)d_in[11];
  const float* soff_b  = (const float*)d_in[12];
  const float* attw_w  = (const float*)d_in[13];
  const float* attw_b  = (const float*)d_in[14];
  const float* mop_w   = (const float*)d_in[15];
  const float* mop_b   = (const float*)d_in[16];
  const float* dout_w  = (const float*)d_in[17];
  const float* dout_b  = (const float*)d_in[18];
  const float* ln3_g   = (const float*)d_in[19];
  const float* ln3_b   = (const float*)d_in[20];
  const float* geglu_w = (const float*)d_in[21];
  const float* geglu_b = (const float*)d_in[22];
  const float* dense_w = (const float*)d_in[23];
  const float* dense_b = (const float*)d_in[24];
  const float* pout_w  = (const float*)d_in[25];
  const float* pout_b  = (const float*)d_in[26];
  float* out = (float*)d_out;

  char* ws = (char*)d_ws;
  size_t off = 0;
  auto alloc = [&](size_t bytes) -> char* {
    off = (off + 255) & ~(size_t)255;
    char* p = ws + off;
    off += bytes;
    return p;
  };
  // persistent weights (bf16, transposed)
  bf16* wtPin   = (bf16*)alloc(512 * 512 * 2);
  bf16* wtBig   = (bf16*)alloc(768 * 512 * 2);     // [vproj 512 | soff 128 | attw 64 | pad 64]
  bf16* wtMvp   = (bf16*)alloc(512 * 512 * 2);
  bf16* wtMop   = (bf16*)alloc(512 * 512 * 2);
  bf16* wtDout  = (bf16*)alloc(512 * 512 * 2);
  bf16* wtPout  = (bf16*)alloc(512 * 512 * 2);
  bf16* wtGeglu = (bf16*)alloc((size_t)4096 * 512 * 2);   // granule-16 interleaved
  bf16* wtDense = (bf16*)alloc((size_t)512 * 2048 * 2);
  float* biasBig = (float*)alloc(768 * 4);
  float* stats   = (float*)alloc(64 * 4);
  // activation regions with liveness-checked unions
  char* A  = alloc(32 * MB);  // t32 (early) | hn@0 (16MB) + t3@16MB
  char* Cg = alloc(32 * MB);  // t2 (fp32)
  char* D  = alloc(64 * MB);  // xnt@0, v@16, v2@32, msda@48
  char* E  = alloc(64 * MB);  // q16@0, sa32@16 (16MB), m2@32 (16MB) | ffin@0 (64MB)
  if (off > ws_size) return;  // workspace too small — fail loudly (zero output)

  float* t32   = (float*)A;
  bf16*  hn    = (bf16*)A;
  bf16*  t3    = (bf16*)(A + 16 * MB);
  float* t2    = (float*)Cg;
  bf16*  xnt   = (bf16*)D;
  bf16*  v16   = (bf16*)(D + 16 * MB);
  bf16*  v2b   = (bf16*)(D + 32 * MB);
  bf16*  msda  = (bf16*)(D + 48 * MB);
  bf16*  q16   = (bf16*)E;
  float* sa32  = (float*)(E + 16 * MB);
  bf16*  m2    = (bf16*)(E + 32 * MB);
  bf16*  ffin  = (bf16*)E;

  hipMemsetAsync(stats, 0, 64 * 4, stream);
  pack_bias_big<<<3, 256, 0, stream>>>(vproj_b, soff_b, attw_b, biasBig);

  // fused transpose: 11 jobs
  TransJobs J{};
  auto setJob = [&](int j, const float* src, bf16* dst, int K, int N, int Npad,
                    int ss, int sc, int a, int b) {
    J.src[j] = src; J.dst[j] = dst; J.K[j] = K; J.N[j] = N;
    J.srcStride[j] = ss; J.srcColOff[j] = sc; J.a[j] = a; J.b[j] = b;
    J.tileStart[j + 1] = J.tileStart[j] + (K / 32) * (Npad / 32);
  };
  J.tileStart[0] = 0;
  setJob(0,  pin_w,   wtPin,   512, 512,  512,  512,  0,    1, 0);
  setJob(1,  vproj_w, wtBig,   512, 512,  512,  512,  0,    1, 0);
  setJob(2,  soff_w,  wtBig,   512, 128,  128,  128,  0,    1, 512);
  setJob(3,  attw_w,  wtBig,   512, 64,   128,  64,   0,    1, 640);
  setJob(4,  mvp_w,   wtMvp,   512, 512,  512,  512,  0,    1, 0);
  setJob(5,  mop_w,   wtMop,   512, 512,  512,  512,  0,    1, 0);
  setJob(6,  dout_w,  wtDout,  512, 512,  512,  512,  0,    1, 0);
  setJob(7,  pout_w,  wtPout,  512, 512,  512,  512,  0,    1, 0);
  setJob(8,  geglu_w, wtGeglu, 512, 2048, 2048, 4096, 0,    2, 0);  // a-half
  setJob(9,  geglu_w, wtGeglu, 512, 2048, 2048, 4096, 2048, 2, 1);  // gate-half
  setJob(10, dense_w, wtDense, 2048, 512, 512,  512,  0,    1, 0);
  transpose_all<<<J.tileStart[11], dim3(32, 8), 0, stream>>>(J);

  dim3 tb(32, 8);
  gn_partial<<<512, 256, 0, stream>>>(x, stats);
  gn_apply_t<<<dim3(128, 16, 4), tb, 0, stream>>>(x, stats, gn_g, gn_b, xnt);

  // t = xnt @ pin + b   (fp32 trunk)
  gemm_bt<float, float, 0><<<dim3(4, 128), 256, 0, stream>>>(
      xnt, wtPin, pin_b, nullptr, t32, nullptr, M_, 512, 512);
  // q = LN1(t)
  layernorm_k<<<4096, 256, 0, stream>>>(t32, ln1_g, ln1_b, q16);
  // fused: value = q @ vproj (bf16) ; sa = q @ [soff|attw] (fp32)
  gemm_bt<bf16, float, 4><<<dim3(6, 128), 256, 0, stream>>>(
      q16, wtBig, biasBig, nullptr, v16, sa32, M_, 768, 512);
  // v2 = value @ mvp
  gemm_bt<bf16, float, 0><<<dim3(4, 128), 256, 0, stream>>>(
      v16, wtMvp, mvp_b, nullptr, v2b, nullptr, M_, 512, 512);
  msda_k<<<32768, 256, 0, stream>>>(sa32, v2b, msda);
  // m2 = msda @ mop + b + q ; t2 = m2 @ dout + b + t (fp32 trunk)
  gemm_bt<bf16, bf16, 1><<<dim3(4, 128), 256, 0, stream>>>(
      msda, wtMop, mop_b, q16, m2, nullptr, M_, 512, 512);
  gemm_bt<float, float, 1><<<dim3(4, 128), 256, 0, stream>>>(
      m2, wtDout, dout_b, t32, t2, nullptr, M_, 512, 512);
  // hn = LN3(t2)
  layernorm_k<<<4096, 256, 0, stream>>>(t2, ln3_g, ln3_b, hn);
  // ffin = (hn @ Wa + ba) * gelu(hn @ Wg + bg)   — interleaved GEGLU, N=4096
  gemm_geglu2<<<dim3(32, 128), 256, 0, stream>>>(hn, wtGeglu, geglu_b, ffin, 512);
  // t3 = ffin @ dense + b + t2
  gemm_bt<bf16, float, 1><<<dim3(4, 128), 256, 0, stream>>>(
      ffin, wtDense, dense_b, t2, t3, nullptr, M_, 512, 2048);
  // out[b,c,l] = (t3 @ pout + b)[b,l,c] + x[b,c,l]   (fused transpose epilogue)
  gemm_bt<float, float, 3><<<dim3(4, 128), 256, 0, stream>>>(
      t3, wtPout, pout_b, x, out, nullptr, M_, 512, 512);
}

// Round 9
// 511.404 us; speedup vs baseline: 1.2960x; 1.0051x over previous
//
#include <hip/hip_runtime.h>
#include <hip/hip_bf16.h>
#include <math.h>

using bf16 = __hip_bfloat16;
typedef __attribute__((ext_vector_type(8))) short short8;
typedef __attribute__((ext_vector_type(4))) float f32x4;

static constexpr int B_ = 4, C_ = 512, L_ = 4096, M_ = 16384;
static constexpr size_t MB = 1ull << 20;

__device__ __forceinline__ float b2f(bf16 v){ return __bfloat162float(v); }
__device__ __forceinline__ bf16  f2b(float v){ return __float2bfloat16(v); }

// async global -> LDS, 16B per lane, lane l lands at (wave-uniform base) + l*16
__device__ __forceinline__ void gl_lds16(const bf16* g, bf16* l) {
  __builtin_amdgcn_global_load_lds(
      (const __attribute__((address_space(1))) unsigned int*)g,
      (__attribute__((address_space(3))) unsigned int*)l, 16, 0, 0);
}

// gelu(g) = 0.5 g (1 + erf(g/sqrt2)); erf via A&S 7.1.26 (|eps| < 1.5e-7)
__device__ __forceinline__ float fast_gelu(float g) {
  float t  = g * 0.70710678118654752f;
  float at = fabsf(t);
  float k  = 1.f / (1.f + 0.3275911f * at);
  float poly = k * (0.254829592f + k * (-0.284496736f + k * (1.421413741f +
               k * (-1.453152027f + k * 1.061405429f))));
  float erfv = 1.f - poly * __expf(-at * at);
  erfv = __builtin_copysignf(erfv, t);
  return 0.5f * g * (1.f + erfv);
}

// ---------------- fused weight transpose: 11 jobs in one dispatch ----------
// mode a==1: dst row = n + b.  mode a==2: granule-16 geglu interleave:
//   dst row = ((n>>4)<<5) + b*16 + (n&15)   (b=0: a-half, b=1: gate-half)
struct TransJobs {
  const float* src[11];
  bf16* dst[11];
  int K[11], N[11], srcStride[11], srcColOff[11], a[11], b[11];
  int tileStart[12];
};

__global__ __launch_bounds__(256) void transpose_all(TransJobs J)
{
  __shared__ float tile[32][33];
  int t = blockIdx.x;
  int j = 0;
  #pragma unroll
  for (int q = 0; q < 10; q++) if (t >= J.tileStart[q + 1]) j = q + 1;
  t -= J.tileStart[j];
  const int kTiles = J.K[j] >> 5;
  const int k0 = (t % kTiles) * 32, n0 = (t / kTiles) * 32;
  const int tx = threadIdx.x, ty = threadIdx.y;
  const float* src = J.src[j];
  const int N = J.N[j], ss = J.srcStride[j], sc = J.srcColOff[j];
  #pragma unroll
  for (int i = 0; i < 32; i += 8) {
    int k = k0 + ty + i, n = n0 + tx;
    tile[ty + i][tx] = (n < N) ? src[(size_t)k * ss + sc + n] : 0.f;
  }
  __syncthreads();
  bf16* dst = J.dst[j];
  const int a = J.a[j], b = J.b[j], K = J.K[j];
  #pragma unroll
  for (int i = 0; i < 32; i += 8) {
    int n = n0 + ty + i, k = k0 + tx;
    int row = (a == 2) ? (((n >> 4) << 5) + b * 16 + (n & 15)) : (n + b);
    dst[(size_t)row * K + k] = f2b(tile[tx][ty + i]);
  }
}

// combined bias [vproj(512) | soff(128) | attw(64) | zero(64)]
__global__ void pack_bias_big(const float* __restrict__ vb,
    const float* __restrict__ sb, const float* __restrict__ ab,
    float* __restrict__ bp){
  int i = blockIdx.x * 256 + threadIdx.x;   // 768 threads
  float v = 0.f;
  if (i < 512) v = vb[i];
  else if (i < 640) v = sb[i - 512];
  else if (i < 704) v = ab[i - 640];
  bp[i] = v;
}

// ---------------- GroupNorm stats (sum, sumsq per (b,g)) ----------------
__global__ __launch_bounds__(256) void gn_partial(const float* __restrict__ x,
                                                  float* __restrict__ stats)
{
  int bg = blockIdx.x >> 4;
  int sc = blockIdx.x & 15;
  size_t base = (size_t)bg * 262144 + (size_t)sc * 16384;
  int tid = threadIdx.x;
  float s = 0.f, s2 = 0.f;
  #pragma unroll
  for (int i = 0; i < 8; i++) {
    size_t o = base + ((size_t)i * 256 + tid) * 8;
    float4 a = *reinterpret_cast<const float4*>(&x[o]);
    float4 b = *reinterpret_cast<const float4*>(&x[o + 4]);
    s  += a.x + a.y + a.z + a.w + b.x + b.y + b.z + b.w;
    s2 += a.x*a.x + a.y*a.y + a.z*a.z + a.w*a.w
        + b.x*b.x + b.y*b.y + b.z*b.z + b.w*b.w;
  }
  #pragma unroll
  for (int o = 32; o; o >>= 1) { s += __shfl_xor(s, o, 64); s2 += __shfl_xor(s2, o, 64); }
  __shared__ float ls[4], ls2[4];
  int wave = tid >> 6, lane = tid & 63;
  if (lane == 0) { ls[wave] = s; ls2[wave] = s2; }
  __syncthreads();
  if (tid == 0) {
    atomicAdd(&stats[bg * 2 + 0], ls[0] + ls[1] + ls[2] + ls[3]);
    atomicAdd(&stats[bg * 2 + 1], ls2[0] + ls2[1] + ls2[2] + ls2[3]);
  }
}

// ---------------- GN apply + transpose (B,C,L) -> (B*L, C) bf16 ----------
__global__ __launch_bounds__(256) void gn_apply_t(const float* __restrict__ x,
    const float* __restrict__ stats, const float* __restrict__ gg,
    const float* __restrict__ gb, bf16* __restrict__ xnt)
{
  __shared__ float tile[32][33];
  int b = blockIdx.z, c0 = blockIdx.y * 32, l0 = blockIdx.x * 32;
  int tx = threadIdx.x, ty = threadIdx.y;
  #pragma unroll
  for (int i = 0; i < 32; i += 8) {
    int c = c0 + ty + i, l = l0 + tx;
    int grp = b * 8 + (c >> 6);
    float sum = stats[grp * 2], ss = stats[grp * 2 + 1];
    float mu = sum * (1.f / 262144.f);
    float inv = rsqrtf(ss * (1.f / 262144.f) - mu * mu + 1e-5f);
    float v = x[((size_t)b * 512 + c) * 4096 + l];
    tile[ty + i][tx] = (v - mu) * inv * gg[c] + gb[c];
  }
  __syncthreads();
  #pragma unroll
  for (int i = 0; i < 32; i += 8) {
    int l = l0 + ty + i, c = c0 + tx;
    xnt[((size_t)b * 4096 + l) * 512 + c] = f2b(tile[tx][ty + i]);
  }
}

// ---------------- LayerNorm over C=512: fp32 in, bf16 out, 1 wave/row -----
__global__ __launch_bounds__(256) void layernorm_k(const float* __restrict__ X,
    const float* __restrict__ g, const float* __restrict__ b, bf16* __restrict__ Y)
{
  int row = blockIdx.x * 4 + (threadIdx.x >> 6);
  int lane = threadIdx.x & 63;
  const float* xr = X + (size_t)row * 512 + lane * 8;
  float4 a = *reinterpret_cast<const float4*>(xr);
  float4 c = *reinterpret_cast<const float4*>(xr + 4);
  float v[8] = {a.x, a.y, a.z, a.w, c.x, c.y, c.z, c.w};
  float s = 0.f, s2 = 0.f;
  #pragma unroll
  for (int i = 0; i < 8; i++) { s += v[i]; s2 += v[i] * v[i]; }
  #pragma unroll
  for (int o = 32; o; o >>= 1) { s += __shfl_xor(s, o, 64); s2 += __shfl_xor(s2, o, 64); }
  float mu = s * (1.f / 512.f);
  float inv = rsqrtf(s2 * (1.f / 512.f) - mu * mu + 1e-5f);
  float4 g0 = *reinterpret_cast<const float4*>(&g[lane * 8]);
  float4 g1 = *reinterpret_cast<const float4*>(&g[lane * 8 + 4]);
  float4 b0 = *reinterpret_cast<const float4*>(&b[lane * 8]);
  float4 b1 = *reinterpret_cast<const float4*>(&b[lane * 8 + 4]);
  float gv[8] = {g0.x, g0.y, g0.z, g0.w, g1.x, g1.y, g1.z, g1.w};
  float bv[8] = {b0.x, b0.y, b0.z, b0.w, b1.x, b1.y, b1.z, b1.w};
  bf16 outv[8];
  #pragma unroll
  for (int i = 0; i < 8; i++) outv[i] = f2b((v[i] - mu) * inv * gv[i] + bv[i]);
  *reinterpret_cast<uint4*>(Y + (size_t)row * 512 + lane * 8) =
      *reinterpret_cast<const uint4*>(outv);
}

// --- MFMA GEMM, 128x128 tile, 512 threads (8 waves, 2x4 frags/wave) -------
// BK=64 full-line staging + XOR swizzle, dbuf. LDS 64 KB -> 2 blocks/CU,
// 16 waves/CU = 4 waves/SIMD (TLP to hide ds_read latency + barrier drain).
// EPI: 0 none | 1 += res[idx] | 3 transpose+residual fp32 out
// EPI 4: n0<512 -> bf16 Cv[m*512+n]; n0>=512 -> fp32 out2[m*256+n-512]
template<typename TOUT, typename TRES, int EPI>
__global__ __launch_bounds__(512) void gemm_bt(const bf16* __restrict__ A,
    const bf16* __restrict__ Bt, const float* __restrict__ bias,
    const TRES* __restrict__ res, TOUT* __restrict__ Cv,
    float* __restrict__ out2, int M, int N, int K)
{
  __shared__ alignas(16) bf16 As[2][128 * 64];
  __shared__ alignas(16) bf16 Bs[2][128 * 64];
  const int tid = threadIdx.x;
  const int m0 = blockIdx.y * 128;
  const int n0 = blockIdx.x * 128;
  const int lane = tid & 63;
  const int wave = tid >> 6;            // 0..7
  const int wm = (wave & 3) * 32;       // 4 m-strips of 32 rows
  const int wn = (wave >> 2) * 64;      // 2 n-strips of 64 cols
  const int fr = lane & 15;
  const int fq = lane >> 4;
  const int sr8 = lane >> 3;                    // row within 8-row staging group
  const int sgl = ((lane & 7) ^ sr8) * 8;       // swizzled source granule (elems)

  const bf16* gaBase = A  + (size_t)(m0 + wave * 16 + sr8) * K + sgl;
  const bf16* gbBase = Bt + (size_t)(n0 + wave * 16 + sr8) * K + sgl;

  f32x4 acc[2][4];
  #pragma unroll
  for (int i = 0; i < 2; i++)
    #pragma unroll
    for (int j = 0; j < 4; j++) acc[i][j] = (f32x4){0.f, 0.f, 0.f, 0.f};

  auto stage = [&](int buf, int kt) {
    const bf16* ga = gaBase + kt;
    const bf16* gb = gbBase + kt;
    bf16* la = &As[buf][wave * 16 * 64];
    bf16* lb = &Bs[buf][wave * 16 * 64];
    gl_lds16(ga, la);                    gl_lds16(ga + (size_t)8 * K, la + 8 * 64);
    gl_lds16(gb, lb);                    gl_lds16(gb + (size_t)8 * K, lb + 8 * 64);
  };

  stage(0, 0);
  int cur = 0;
  for (int kt = 0; kt < K; kt += 64) {
    __syncthreads();                            // drains stage(cur)
    if (kt + 64 < K) stage(cur ^ 1, kt + 64);   // async prefetch next tile
    #pragma unroll
    for (int ko = 0; ko < 2; ko++) {
      const int pa = ((ko * 4 + fq) ^ (fr & 7)) * 8;
      short8 af[2], bfv[4];
      #pragma unroll
      for (int mi = 0; mi < 2; mi++)
        af[mi] = *reinterpret_cast<const short8*>(&As[cur][(wm + mi * 16 + fr) * 64 + pa]);
      #pragma unroll
      for (int ni = 0; ni < 4; ni++)
        bfv[ni] = *reinterpret_cast<const short8*>(&Bs[cur][(wn + ni * 16 + fr) * 64 + pa]);
      #pragma unroll
      for (int mi = 0; mi < 2; mi++)
        #pragma unroll
        for (int ni = 0; ni < 4; ni++)
          acc[mi][ni] = __builtin_amdgcn_mfma_f32_16x16x32_bf16(af[mi], bfv[ni],
                                                                acc[mi][ni], 0, 0, 0);
    }
    cur ^= 1;
  }

  // epilogue: C/D layout col = lane&15, row = (lane>>4)*4 + reg
  #pragma unroll
  for (int ni = 0; ni < 4; ni++) {
    int n = n0 + wn + ni * 16 + fr;
    float bv = bias[n];
    #pragma unroll
    for (int mi = 0; mi < 2; mi++) {
      int mbase = m0 + wm + mi * 16 + fq * 4;
      if (EPI == 3) {
        int b = mbase >> 12, l = mbase & 4095;
        size_t o = ((size_t)(b * 512 + n) << 12) + l;
        float4 xr = *reinterpret_cast<const float4*>(&((const float*)res)[o]);
        float4 vv;
        vv.x = acc[mi][ni][0] + bv + xr.x;
        vv.y = acc[mi][ni][1] + bv + xr.y;
        vv.z = acc[mi][ni][2] + bv + xr.z;
        vv.w = acc[mi][ni][3] + bv + xr.w;
        *reinterpret_cast<float4*>(&((float*)Cv)[o]) = vv;
      } else if (EPI == 4) {
        #pragma unroll
        for (int r = 0; r < 4; r++) {
          float v = acc[mi][ni][r] + bv;
          if (n0 < 512) ((bf16*)Cv)[(size_t)(mbase + r) * 512 + n] = f2b(v);
          else          out2[(size_t)(mbase + r) * 256 + (n - 512)] = v;
        }
      } else {
        #pragma unroll
        for (int r = 0; r < 4; r++) {
          size_t idx = (size_t)(mbase + r) * N + n;
          float v = acc[mi][ni][r] + bv;
          if (EPI == 1) {
            float rv;
            if constexpr (sizeof(TRES) == 2) rv = b2f(((const bf16*)res)[idx]);
            else                             rv = ((const float*)res)[idx];
            v += rv;
          }
          if constexpr (sizeof(TOUT) == 2) ((bf16*)Cv)[idx] = f2b(v);
          else                             ((float*)Cv)[idx] = v;
        }
      }
    }
  }
}

// --- GEGLU GEMM, 512 threads, granule-16 N-interleave + BK=64 swizzle -----
// Wt rows 32j..32j+15 = Wa cols 16j..16j+15; rows 32j+16..32j+31 = Wg same.
// a and g land in the SAME lane: acc[mi][2p]=a, acc[mi][2p+1]=g.
__global__ __launch_bounds__(512) void gemm_geglu2(const bf16* __restrict__ A,
    const bf16* __restrict__ Wt, const float* __restrict__ gb,
    bf16* __restrict__ Cv, int K)
{
  __shared__ alignas(16) bf16 As[2][128 * 64];
  __shared__ alignas(16) bf16 Bs[2][128 * 64];
  const int tid = threadIdx.x;
  const int m0 = blockIdx.y * 128;
  const int n0 = blockIdx.x * 128;       // interleaved-row space (0..4095)
  const int lane = tid & 63;
  const int wave = tid >> 6;
  const int wm = (wave & 3) * 32;
  const int wn = (wave >> 2) * 64;
  const int fr = lane & 15;
  const int fq = lane >> 4;
  const int sr8 = lane >> 3;
  const int sgl = ((lane & 7) ^ sr8) * 8;

  const bf16* gaBase = A  + (size_t)(m0 + wave * 16 + sr8) * K + sgl;
  const bf16* gbBase = Wt + (size_t)(n0 + wave * 16 + sr8) * K + sgl;

  f32x4 acc[2][4];
  #pragma unroll
  for (int i = 0; i < 2; i++)
    #pragma unroll
    for (int j = 0; j < 4; j++) acc[i][j] = (f32x4){0.f, 0.f, 0.f, 0.f};

  auto stage = [&](int buf, int kt) {
    const bf16* ga = gaBase + kt;
    const bf16* gb2 = gbBase + kt;
    bf16* la = &As[buf][wave * 16 * 64];
    bf16* lb = &Bs[buf][wave * 16 * 64];
    gl_lds16(ga, la);                    gl_lds16(ga + (size_t)8 * K, la + 8 * 64);
    gl_lds16(gb2, lb);                   gl_lds16(gb2 + (size_t)8 * K, lb + 8 * 64);
  };

  stage(0, 0);
  int cur = 0;
  for (int kt = 0; kt < K; kt += 64) {
    __syncthreads();
    if (kt + 64 < K) stage(cur ^ 1, kt + 64);
    #pragma unroll
    for (int ko = 0; ko < 2; ko++) {
      const int pa = ((ko * 4 + fq) ^ (fr & 7)) * 8;
      short8 af[2], bfv[4];
      #pragma unroll
      for (int mi = 0; mi < 2; mi++)
        af[mi] = *reinterpret_cast<const short8*>(&As[cur][(wm + mi * 16 + fr) * 64 + pa]);
      #pragma unroll
      for (int ni = 0; ni < 4; ni++)
        bfv[ni] = *reinterpret_cast<const short8*>(&Bs[cur][(wn + ni * 16 + fr) * 64 + pa]);
      #pragma unroll
      for (int mi = 0; mi < 2; mi++)
        #pragma unroll
        for (int ni = 0; ni < 4; ni++)
          acc[mi][ni] = __builtin_amdgcn_mfma_f32_16x16x32_bf16(af[mi], bfv[ni],
                                                                acc[mi][ni], 0, 0, 0);
    }
    cur ^= 1;
  }

  const int cbase = (n0 + wn) >> 1;
  #pragma unroll
  for (int pi = 0; pi < 2; pi++) {
    int col = cbase + pi * 16 + fr;
    float ba = gb[col];
    float bg = gb[2048 + col];
    #pragma unroll
    for (int mi = 0; mi < 2; mi++) {
      int mbase = m0 + wm + mi * 16 + fq * 4;
      #pragma unroll
      for (int r = 0; r < 4; r++) {
        float a = acc[mi][2 * pi][r] + ba;
        float g = acc[mi][2 * pi + 1][r] + bg;
        Cv[(size_t)(mbase + r) * 2048 + col] = f2b(a * fast_gelu(g));
      }
    }
  }
}

// ---------------- MSDA: degenerate deformable attention (Hl=L, Wl=1) ------
// sa: [M][256] fp32: cols 0..127 = sampling offsets, 128..191 = attn logits
__global__ __launch_bounds__(256) void msda_k(const float* __restrict__ sa,
    const bf16* __restrict__ v2, bf16* __restrict__ outp)
{
  int unit = blockIdx.x * 4 + (threadIdx.x >> 6);  // (b*L+l)*8 + h
  int lane = threadIdx.x & 63;
  int m = unit >> 3;
  int h = unit & 7;
  int b = m >> 12;                                  // L = 4096
  const float* lg = &sa[(size_t)m * 256 + 128 + h * 8];
  float w[8], mx = -1e30f;
  #pragma unroll
  for (int p = 0; p < 8; p++) { w[p] = lg[p]; mx = fmaxf(mx, w[p]); }
  float sum = 0.f;
  #pragma unroll
  for (int p = 0; p < 8; p++) { w[p] = expf(w[p] - mx); sum += w[p]; }
  float rs = 1.f / sum;
  const float* op = &sa[(size_t)m * 256 + h * 16];
  size_t vbase = ((size_t)b * 4096) * 512 + h * 64 + lane;
  float acc = 0.f;
  #pragma unroll
  for (int p = 0; p < 8; p++) {
    float ox = op[p * 2 + 0], oy = op[p * 2 + 1];
    float gx = 2.f * (0.5f + ox) - 1.f;
    float px = ((gx + 1.f) * 1.f - 1.f) * 0.5f;              // = ox (mirrors ref fp ops)
    float gy = 2.f * (0.5f + oy * (1.f / 4096.f)) - 1.f;
    float py = ((gy + 1.f) * 4096.f - 1.f) * 0.5f;           // = oy + 2047.5
    float x0 = floorf(px), y0 = floorf(py);
    float lx = px - x0, ly = py - y0;
    int xi = (int)x0;
    int yi = (int)y0;
    float wx = (xi == 0) ? (1.f - lx) : ((xi == -1) ? lx : 0.f);
    if (wx != 0.f) {                         // wave-uniform branch
      float s = 0.f;
      if (yi >= 0 && yi < 4096)  s += (1.f - ly) * b2f(v2[vbase + (size_t)yi * 512]);
      if (yi >= -1 && yi < 4095) s += ly * b2f(v2[vbase + (size_t)(yi + 1) * 512]);
      acc += w[p] * rs * wx * s;
    }
  }
  outp[(size_t)m * 512 + h * 64 + lane] = f2b(acc);
}

// =========================================================================
extern "C" void kernel_launch(void* const* d_in, const int* in_sizes, int n_in,
                              void* d_out, int out_size, void* d_ws, size_t ws_size,
                              hipStream_t stream)
{
  if (n_in < 27) return;
  const float* x       = (const float*)d_in[0];
  const float* gn_g    = (const float*)d_in[1];
  const float* gn_b    = (const float*)d_in[2];
  const float* pin_w   = (const float*)d_in[3];
  const float* pin_b   = (const float*)d_in[4];
  const float* ln1_g   = (const float*)d_in[5];
  const float* ln1_b   = (const float*)d_in[6];
  const float* vproj_w = (const float*)d_in[7];
  const float* vproj_b = (const float*)d_in[8];
  const float* mvp_w   = (const float*)d_in[9];
  const float* mvp_b   = (const float*)d_in[10];
  const float* soff_w  = (const float*)d_in[11];
  const float* soff_b  = (const float*)d_in[12];
  const float* attw_w  = (const float*)d_in[13];
  const float* attw_b  = (const float*)d_in[14];
  const float* mop_w   = (const float*)d_in[15];
  const float* mop_b   = (const float*)d_in[16];
  const float* dout_w  = (const float*)d_in[17];
  const float* dout_b  = (const float*)d_in[18];
  const float* ln3_g   = (const float*)d_in[19];
  const float* ln3_b   = (const float*)d_in[20];
  const float* geglu_w = (const float*)d_in[21];
  const float* geglu_b = (const float*)d_in[22];
  const float* dense_w = (const float*)d_in[23];
  const float* dense_b = (const float*)d_in[24];
  const float* pout_w  = (const float*)d_in[25];
  const float* pout_b  = (const float*)d_in[26];
  float* out = (float*)d_out;

  char* ws = (char*)d_ws;
  size_t off = 0;
  auto alloc = [&](size_t bytes) -> char* {
    off = (off + 255) & ~(size_t)255;
    char* p = ws + off;
    off += bytes;
    return p;
  };
  // persistent weights (bf16, transposed)
  bf16* wtPin   = (bf16*)alloc(512 * 512 * 2);
  bf16* wtBig   = (bf16*)alloc(768 * 512 * 2);     // [vproj 512 | soff 128 | attw 64 | pad 64]
  bf16* wtMvp   = (bf16*)alloc(512 * 512 * 2);
  bf16* wtMop   = (bf16*)alloc(512 * 512 * 2);
  bf16* wtDout  = (bf16*)alloc(512 * 512 * 2);
  bf16* wtPout  = (bf16*)alloc(512 * 512 * 2);
  bf16* wtGeglu = (bf16*)alloc((size_t)4096 * 512 * 2);   // granule-16 interleaved
  bf16* wtDense = (bf16*)alloc((size_t)512 * 2048 * 2);
  float* biasBig = (float*)alloc(768 * 4);
  float* stats   = (float*)alloc(64 * 4);
  // activation regions with liveness-checked unions
  char* A  = alloc(32 * MB);  // t32 (early) | hn@0 (16MB) + t3@16MB
  char* Cg = alloc(32 * MB);  // t2 (fp32)
  char* D  = alloc(64 * MB);  // xnt@0, v@16, v2@32, msda@48
  char* E  = alloc(64 * MB);  // q16@0, sa32@16 (16MB), m2@32 (16MB) | ffin@0 (64MB)
  if (off > ws_size) return;  // workspace too small — fail loudly (zero output)

  float* t32   = (float*)A;
  bf16*  hn    = (bf16*)A;
  bf16*  t3    = (bf16*)(A + 16 * MB);
  float* t2    = (float*)Cg;
  bf16*  xnt   = (bf16*)D;
  bf16*  v16   = (bf16*)(D + 16 * MB);
  bf16*  v2b   = (bf16*)(D + 32 * MB);
  bf16*  msda  = (bf16*)(D + 48 * MB);
  bf16*  q16   = (bf16*)E;
  float* sa32  = (float*)(E + 16 * MB);
  bf16*  m2    = (bf16*)(E + 32 * MB);
  bf16*  ffin  = (bf16*)E;

  hipMemsetAsync(stats, 0, 64 * 4, stream);
  pack_bias_big<<<3, 256, 0, stream>>>(vproj_b, soff_b, attw_b, biasBig);

  // fused transpose: 11 jobs
  TransJobs J{};
  auto setJob = [&](int j, const float* src, bf16* dst, int K, int N, int Npad,
                    int ss, int sc, int a, int b) {
    J.src[j] = src; J.dst[j] = dst; J.K[j] = K; J.N[j] = N;
    J.srcStride[j] = ss; J.srcColOff[j] = sc; J.a[j] = a; J.b[j] = b;
    J.tileStart[j + 1] = J.tileStart[j] + (K / 32) * (Npad / 32);
  };
  J.tileStart[0] = 0;
  setJob(0,  pin_w,   wtPin,   512, 512,  512,  512,  0,    1, 0);
  setJob(1,  vproj_w, wtBig,   512, 512,  512,  512,  0,    1, 0);
  setJob(2,  soff_w,  wtBig,   512, 128,  128,  128,  0,    1, 512);
  setJob(3,  attw_w,  wtBig,   512, 64,   128,  64,   0,    1, 640);
  setJob(4,  mvp_w,   wtMvp,   512, 512,  512,  512,  0,    1, 0);
  setJob(5,  mop_w,   wtMop,   512, 512,  512,  512,  0,    1, 0);
  setJob(6,  dout_w,  wtDout,  512, 512,  512,  512,  0,    1, 0);
  setJob(7,  pout_w,  wtPout,  512, 512,  512,  512,  0,    1, 0);
  setJob(8,  geglu_w, wtGeglu, 512, 2048, 2048, 4096, 0,    2, 0);  // a-half
  setJob(9,  geglu_w, wtGeglu, 512, 2048, 2048, 4096, 2048, 2, 1);  // gate-half
  setJob(10, dense_w, wtDense, 2048, 512, 512,  512,  0,    1, 0);
  transpose_all<<<J.tileStart[11], dim3(32, 8), 0, stream>>>(J);

  dim3 tb(32, 8);
  gn_partial<<<512, 256, 0, stream>>>(x, stats);
  gn_apply_t<<<dim3(128, 16, 4), tb, 0, stream>>>(x, stats, gn_g, gn_b, xnt);

  // t = xnt @ pin + b   (fp32 trunk)
  gemm_bt<float, float, 0><<<dim3(4, 128), 512, 0, stream>>>(
      xnt, wtPin, pin_b, nullptr, t32, nullptr, M_, 512, 512);
  // q = LN1(t)
  layernorm_k<<<4096, 256, 0, stream>>>(t32, ln1_g, ln1_b, q16);
  // fused: value = q @ vproj (bf16) ; sa = q @ [soff|attw] (fp32)
  gemm_bt<bf16, float, 4><<<dim3(6, 128), 512, 0, stream>>>(
      q16, wtBig, biasBig, nullptr, v16, sa32, M_, 768, 512);
  // v2 = value @ mvp
  gemm_bt<bf16, float, 0><<<dim3(4, 128), 512, 0, stream>>>(
      v16, wtMvp, mvp_b, nullptr, v2b, nullptr, M_, 512, 512);
  msda_k<<<32768, 256, 0, stream>>>(sa32, v2b, msda);
  // m2 = msda @ mop + b + q ; t2 = m2 @ dout + b + t (fp32 trunk)
  gemm_bt<bf16, bf16, 1><<<dim3(4, 128), 512, 0, stream>>>(
      msda, wtMop, mop_b, q16, m2, nullptr, M_, 512, 512);
  gemm_bt<float, float, 1><<<dim3(4, 128), 512, 0, stream>>>(
      m2, wtDout, dout_b, t32, t2, nullptr, M_, 512, 512);
  // hn = LN3(t2)
  layernorm_k<<<4096, 256, 0, stream>>>(t2, ln3_g, ln3_b, hn);
  // ffin = (hn @ Wa + ba) * gelu(hn @ Wg + bg)   — interleaved GEGLU, N=4096
  gemm_geglu2<<<dim3(32, 128), 512, 0, stream>>>(hn, wtGeglu, geglu_b, ffin, 512);
  // t3 = ffin @ dense + b + t2
  gemm_bt<bf16, float, 1><<<dim3(4, 128), 512, 0, stream>>>(
      ffin, wtDense, dense_b, t2, t3, nullptr, M_, 512, 2048);
  // out[b,c,l] = (t3 @ pout + b)[b,l,c] + x[b,c,l]   (fused transpose epilogue)
  gemm_bt<float, float, 3><<<dim3(4, 128), 512, 0, stream>>>(
      t3, wtPout, pout_b, x, out, nullptr, M_, 512, 512);
}